// Round 14
// baseline (3482.295 us; speedup 1.0000x reference)
//
#include <hip/hip_runtime.h>
#include <hip/hip_bf16.h>

#define NEGF (-1000000000.0f)

namespace {

constexpr int B  = 64;
constexpr int N  = 50;
constexpr int NT = 30;
constexpr int T  = 60;
constexpr int S  = 90;          // NT + T
constexpr int NP1 = N + 1;      // 51
constexpr int NSMAX = N - 1;    // 49
constexpr int SS = S * S;       // 8100
constexpr int CELLS = NT * NSMAX; // 1470
constexpr int ECOUNT = B * NP1 * NP1 * S;

// ---- padded K layout ----
constexpr int KP  = 96;          // padded r-dim per l (erule pads are exact 0)
constexpr int KK  = S * KP;      // 8640
constexpr int KT2 = 64;          // K-tile per LDS staging step
constexpr int NKT = KK / KT2;    // 135 tiles (full K per block now)
constexpr int MLSTR = 72;        // LDS row stride (shorts); 144B: b128-aligned
constexpr int MAROWS = 32;
constexpr int MBROWS = 64;
constexpr int AOFFE = MAROWS * MLSTR;
constexpr int MTOT  = (MAROWS + MBROWS) * MLSTR;   // 6912 shorts = 13.8 KB

// ---- stage1 MFMA layout ----
constexpr int S1R = 96;          // padded state rows: 6 tiles of 16
constexpr int S1STR = 72;        // row stride in shorts (144B, b128-aligned)

using bf16x8 = __attribute__((ext_vector_type(8))) short;
using f32x4  = __attribute__((ext_vector_type(4))) float;

// width-1 spans: mb = state max; E = bf16(exp(unary - mb)) for terminal slots.
// (beta width-1 is never read; E's invalid slots are masked in stage1.)
__global__ void unary_init(const float* __restrict__ unary,
                           float* __restrict__ mb, short* __restrict__ E){
  int k = blockIdx.x, b = blockIdx.y, j = threadIdx.x;
  float v = (j < T) ? unary[(b*N + k)*T + j] : NEGF;
  float m = v;
  #pragma unroll
  for (int off = 32; off > 0; off >>= 1) m = fmaxf(m, __shfl_xor(m, off));
  if (j == 0) mb[(b*NP1 + k)*NP1 + (k+1)] = m;
  if (j < T){
    __hip_bfloat16 h = __float2bfloat16(__expf(v - m));
    E[((b*NP1 + k)*NP1 + (k+1))*S + NT + j] = *reinterpret_cast<short*>(&h);
  }
}

// Vectorized 2-pass rule prep: float4 max pass; float2 -> 2 exps -> packed uint store.
__global__ __launch_bounds__(256) void rule_prep(const float* __restrict__ rule,
                                                 float* __restrict__ m_rule,
                                                 __hip_bfloat16* __restrict__ erule){
  int p = blockIdx.x, b = blockIdx.y, tid = threadIdx.x;
  size_t base = (size_t)(b*NT + p) * SS;
  size_t obase = (size_t)(b*NT + p) * KK;
  const float4* r4 = (const float4*)(rule + base);
  float lm = NEGF;
  for (int i = tid; i < SS/4; i += 256){
    float4 v = r4[i];
    lm = fmaxf(fmaxf(lm, fmaxf(v.x, v.y)), fmaxf(v.z, v.w));
  }
  #pragma unroll
  for (int off = 32; off > 0; off >>= 1) lm = fmaxf(lm, __shfl_xor(lm, off));
  __shared__ float wmax[4];
  __shared__ float sm;
  if ((tid & 63) == 0) wmax[tid >> 6] = lm;
  __syncthreads();
  if (tid == 0){
    float m = fmaxf(fmaxf(wmax[0], wmax[1]), fmaxf(wmax[2], wmax[3]));
    m_rule[b*NT + p] = m;
    sm = m;
  }
  __syncthreads();
  float m = sm;
  for (int idx = tid; idx < S * 48; idx += 256){
    int l = idx / 48, pr = idx - l * 48;
    int r = pr * 2;
    unsigned int out = 0;
    if (r < S){
      float2 v = *(const float2*)(rule + base + l*S + r);
      __hip_bfloat16 h0 = __float2bfloat16(__expf(v.x - m));
      __hip_bfloat16 h1 = __float2bfloat16(__expf(v.y - m));
      out = (unsigned int)*(unsigned short*)&h0 |
            ((unsigned int)*(unsigned short*)&h1 << 16);
    }
    *(unsigned int*)&erule[obase + l*KP + r] = out;
  }
}

// Per span (b,s) of width w: O[l,r] = sum_k el[k,l]*er[k,r] via MFMA.
// E-cache staging (R13) + child-width validity masks (R10) — no E zero-fill.
__global__ __launch_bounds__(256) void stage1(int w, const short* __restrict__ E,
                                              const float* __restrict__ mb,
                                              float* __restrict__ Mbuf,
                                              __hip_bfloat16* __restrict__ Og){
  int s = blockIdx.x, b = blockIdx.y, e = s + w, tid = threadIdx.x;
  int K = w - 1;
  int Kpad = (K + 31) & ~31;          // 32 or 64
  __shared__ float stmp[NSMAX];
  __shared__ float cK[NSMAX];
  __shared__ float sM;
  __shared__ __align__(16) short sbuf[2 * S1R * S1STR];  // 27.6 KB
  short* elT = sbuf;
  short* erT = sbuf + S1R * S1STR;

  if (tid < K){
    int u = s + tid + 1;
    stmp[tid] = mb[(b*NP1 + s)*NP1 + u] + mb[(b*NP1 + u)*NP1 + e];
  }
  __syncthreads();
  if (tid == 0){
    float M = NEGF;
    for (int k = 0; k < K; ++k) M = fmaxf(M, stmp[k]);
    sM = M;
    Mbuf[b*NSMAX + s] = M;
  }
  __syncthreads();
  float M = sM;
  if (tid < K) cK[tid] = __expf(stmp[tid] - M);
  __syncthreads();

  int items = S1R * Kpad;
  for (int idx = tid; idx < items; idx += 256){
    int k = idx / S1R, i = idx - k * S1R;   // i fastest -> coalesced E reads
    short ve = 0, vr = 0;
    if (i < S && k < K){
      int u = s + k + 1;
      // left child width = k+1; right child width = K-k. Width-1 cells hold
      // only terminal states (i>=NT); wider cells only nonterminals (i<NT).
      bool lOK = (k == 0)     ? (i >= NT) : (i < NT);
      bool rOK = (k == K - 1) ? (i >= NT) : (i < NT);
      if (lOK){
        unsigned short eL = (unsigned short)E[((b*NP1 + s)*NP1 + u)*S + i];
        float el = __uint_as_float((unsigned int)eL << 16) * cK[k];
        __hip_bfloat16 he = __float2bfloat16(el);
        ve = *reinterpret_cast<short*>(&he);
      }
      if (rOK) vr = E[((b*NP1 + u)*NP1 + e)*S + i];
    }
    elT[i*S1STR + k] = ve;
    erT[i*S1STR + k] = vr;
  }
  __syncthreads();

  int wid = tid >> 6, lane = tid & 63;
  int rr = lane & 15, hi = lane >> 4;
  int ksteps = Kpad >> 5;
  f32x4 accs[9];
  #pragma unroll
  for (int j = 0; j < 9; ++j){           // 36 tiles over 4 waves
    int t = wid * 9 + j;
    int tr = t / 6, tc = t - tr * 6;
    int ar = tr*16 + rr, br = tc*16 + rr;
    f32x4 acc = {0.f, 0.f, 0.f, 0.f};
    for (int ks = 0; ks < ksteps; ++ks){
      int kb = ks*32 + hi*8;
      bf16x8 af = *(bf16x8*)&elT[ar*S1STR + kb];
      bf16x8 bf2 = *(bf16x8*)&erT[br*S1STR + kb];
      acc = __builtin_amdgcn_mfma_f32_16x16x32_bf16(af, bf2, acc, 0, 0, 0);
    }
    accs[j] = acc;
  }
  __syncthreads();                        // all elT/erT reads done; sbuf reusable

  // repack: bf16 O tile, linear [l*96 + r] in sbuf, then coalesced 16B stores
  short* rep = sbuf;
  for (int idx = tid; idx < S * (KP - S); idx += 256){
    int l = idx / (KP - S), c = idx - l * (KP - S);
    rep[l*KP + S + c] = 0;
  }
  #pragma unroll
  for (int j = 0; j < 9; ++j){
    int t = wid * 9 + j;
    int tr = t / 6, tc = t - tr * 6;
    int rcol = tc*16 + rr;
    if (rcol < S){
      #pragma unroll
      for (int q = 0; q < 4; ++q){
        int l = tr*16 + hi*4 + q;
        if (l < S){
          __hip_bfloat16 h = __float2bfloat16(accs[j][q]);
          rep[l*KP + rcol] = *reinterpret_cast<short*>(&h);
        }
      }
    }
  }
  __syncthreads();

  size_t obase = ((size_t)(b*NSMAX + s)) * KK;
  uint4* dst = (uint4*)(Og + obase);
  const uint4* src = (const uint4*)rep;
  for (int i = tid; i < KK/8; i += 256) dst[i] = src[i];
}

// R14: FUSED stage2+finalize. One block per b (grid=B), 8 waves = 2Mt x 4Nt,
// full K=8640 (135 tiles) with the proven single-barrier reg-dbuf loop; then
// in-block finalize: beta/mb/E. Zero cross-block communication -> no fences.
__global__ __launch_bounds__(512) void stage2f(int w, int ns, int ntiles,
                                               const __hip_bfloat16* __restrict__ erule,
                                               const __hip_bfloat16* __restrict__ Og,
                                               const float* __restrict__ Mbuf,
                                               const float* __restrict__ m_rule,
                                               float* __restrict__ beta,
                                               float* __restrict__ mb,
                                               short* __restrict__ E){
  int b = blockIdx.x, tid = threadIdx.x;
  __shared__ __align__(16) short lds[2 * MTOT];   // 27.6 KB (dbuf)
  __shared__ float smax[NSMAX];
  int wid = tid >> 6, lane = tid & 63;
  int mt = wid & 1, nt = wid >> 1;
  f32x4 acc = {0.f, 0.f, 0.f, 0.f};

  for (int i = tid; i < 2*MTOT; i += 512) lds[i] = 0;

  int slot = tid & 7;
  int aRow = (tid >> 3) & 31;                 // threads 0..255 -> A rows 0..31
  bool aDo = (tid < 256) && (aRow < NT);
  int bRow = tid >> 3;                        // 512 threads -> B rows 0..63
  bool bDo = bRow < ns;
  const __hip_bfloat16* aSrc = erule + ((size_t)(b*NT + (aDo ? aRow : 0))) * KK + slot * 8;
  const __hip_bfloat16* bSrc = Og    + ((size_t)(b*NSMAX + (bDo ? bRow : 0))) * KK + slot * 8;
  int aOff = aRow * MLSTR + slot * 8;
  int bOff = AOFFE + bRow * MLSTR + slot * 8;

  int arow = mt*16 + (lane & 15);
  int brow = nt*16 + (lane & 15);
  int hi = lane >> 4;
  bool active = nt < ntiles;

  uint4 ra, rb;
  if (aDo) ra = *(const uint4*)(aSrc);
  if (bDo) rb = *(const uint4*)(bSrc);
  __syncthreads();   // zero-fill complete before first data writes

  int cur = 0;
  for (int tt = 0; tt < NKT; ++tt){
    if (aDo) *(uint4*)&lds[cur*MTOT + aOff] = ra;
    if (bDo) *(uint4*)&lds[cur*MTOT + bOff] = rb;
    if (tt + 1 < NKT){
      size_t koff = (size_t)(tt + 1) * KT2;
      if (aDo) ra = *(const uint4*)(aSrc + koff);
      if (bDo) rb = *(const uint4*)(bSrc + koff);
    }
    __syncthreads();   // buf[cur] staged; compute(tt-1) on buf[cur^1] done
    if (active){
      #pragma unroll
      for (int ks = 0; ks < 2; ++ks){
        int sb = ks*4 + hi;
        bf16x8 af = *(bf16x8*)&lds[cur*MTOT + arow*MLSTR + sb*8];
        bf16x8 bf2 = *(bf16x8*)&lds[cur*MTOT + AOFFE + brow*MLSTR + sb*8];
        acc = __builtin_amdgcn_mfma_f32_16x16x32_bf16(af, bf2, acc, 0, 0, 0);
      }
    }
    cur ^= 1;
  }

  // ---- in-block finalize ----
  __syncthreads();                 // all MFMA LDS reads done; lds reusable
  float* vals = (float*)lds;       // [scol*NT + p], 5.9 KB
  int scol = nt*16 + (lane & 15);
  if (active && scol < ns){
    float Ms = Mbuf[b*NSMAX + scol];
    #pragma unroll
    for (int r = 0; r < 4; ++r){
      int p = mt*16 + hi*4 + r;
      if (p < NT){
        float v = __logf(fmaxf(acc[r], 1e-37f)) + Ms + m_rule[b*NT + p];
        vals[scol*NT + p] = v;
        beta[((b*NP1 + scol)*NP1 + (scol + w))*S + p] = v;
      }
    }
  }
  __syncthreads();
  if (tid < ns){
    float m = NEGF;
    for (int p = 0; p < NT; ++p) m = fmaxf(m, vals[tid*NT + p]);
    mb[(b*NP1 + tid)*NP1 + (tid + w)] = m;
    smax[tid] = m;
  }
  __syncthreads();
  for (int idx = tid; idx < ns * NT; idx += 512){
    int si = idx / NT, p = idx - si * NT;
    __hip_bfloat16 h = __float2bfloat16(__expf(vals[idx] - smax[si]));
    E[((b*NP1 + si)*NP1 + (si + w))*S + p] = *reinterpret_cast<short*>(&h);
  }
}

__global__ void root_lse(const float* __restrict__ beta, const float* __restrict__ root,
                         float* __restrict__ out){
  int b = blockIdx.x, j = threadIdx.x;
  float v = (j < NT) ? beta[((b*NP1 + 0)*NP1 + N)*S + j] + root[b*NT + j] : NEGF;
  float m = v;
  #pragma unroll
  for (int off = 32; off > 0; off >>= 1) m = fmaxf(m, __shfl_xor(m, off));
  float ex = __expf(v - m);
  #pragma unroll
  for (int off = 32; off > 0; off >>= 1) ex += __shfl_xor(ex, off);
  if (j == 0) out[b] = __logf(ex) + m;
}

} // namespace

extern "C" void kernel_launch(void* const* d_in, const int* in_sizes, int n_in,
                              void* d_out, int out_size, void* d_ws, size_t ws_size,
                              hipStream_t stream){
  (void)in_sizes; (void)n_in; (void)out_size; (void)ws_size;
  const float* unary = (const float*)d_in[0];
  const float* rule  = (const float*)d_in[1];
  const float* root  = (const float*)d_in[2];

  char* ws = (char*)d_ws;
  size_t off = 0;
  auto alloc = [&](size_t bytes) -> void* {
    void* p = ws + off;
    off += (bytes + 255) & ~(size_t)255;
    return p;
  };
  float* beta   = (float*)alloc(sizeof(float) * (size_t)B * NP1 * NP1 * S);
  float* mb     = (float*)alloc(sizeof(float) * (size_t)B * NP1 * NP1);
  float* m_rule = (float*)alloc(sizeof(float) * B * NT);
  float* Mbuf   = (float*)alloc(sizeof(float) * B * NSMAX);
  short* E      = (short*)alloc(sizeof(short) * (size_t)ECOUNT);     // 30 MB bf16
  __hip_bfloat16* erule = (__hip_bfloat16*)alloc(sizeof(__hip_bfloat16) * (size_t)B * NT * KK);
  __hip_bfloat16* Og    = (__hip_bfloat16*)alloc(sizeof(__hip_bfloat16) * (size_t)B * NSMAX * KK);

  unary_init<<<dim3(N, B), dim3(64), 0, stream>>>(unary, mb, E);
  rule_prep<<<dim3(NT, B), dim3(256), 0, stream>>>(rule, m_rule, erule);

  for (int w = 2; w <= N; ++w){
    int ns = N - w + 1;
    int ntiles = (ns + 15) >> 4;
    stage1<<<dim3(ns, B), dim3(256), 0, stream>>>(w, E, mb, Mbuf, Og);
    stage2f<<<dim3(B), dim3(512), 0, stream>>>(w, ns, ntiles, erule, Og,
                                               Mbuf, m_rule, beta, mb, E);
  }
  root_lse<<<dim3(B), dim3(64), 0, stream>>>(beta, root, (float*)d_out);
}

// Round 15
// 1786.748 us; speedup vs baseline: 1.9490x; 1.9490x over previous
//
#include <hip/hip_runtime.h>
#include <hip/hip_bf16.h>

#define NEGF (-1000000000.0f)

namespace {

constexpr int B  = 64;
constexpr int N  = 50;
constexpr int NT = 30;
constexpr int T  = 60;
constexpr int S  = 90;          // NT + T
constexpr int NP1 = N + 1;      // 51
constexpr int NSMAX = N - 1;    // 49
constexpr int SS = S * S;       // 8100
constexpr int CELLS = NT * NSMAX; // 1470
constexpr int ECOUNT = B * NP1 * NP1 * S;

// ---- padded K layout ----
constexpr int KP  = 96;          // padded r-dim per l (erule pads are exact 0)
constexpr int KK  = S * KP;      // 8640
constexpr int KSPL = 15;         // split-K chunks
constexpr int KT2 = 64;          // K-tile per LDS staging step
constexpr int NKT = KK / KT2;    // 135
constexpr int TPC = NKT / KSPL;  // 9 tiles per chunk
constexpr int MLSTR = 72;        // LDS row stride (shorts); 144B: b128-aligned
constexpr int MAROWS = 32;
constexpr int MBROWS = 64;
constexpr int AOFFE = MAROWS * MLSTR;
constexpr int MTOT  = (MAROWS + MBROWS) * MLSTR;   // 6912 shorts = 13.8 KB

// ---- stage1 MFMA layout ----
constexpr int S1R = 96;          // padded state rows: 6 tiles of 16
constexpr int S1STR = 72;        // row stride in shorts (144B, b128-aligned)

using bf16x8 = __attribute__((ext_vector_type(8))) short;
using f32x4  = __attribute__((ext_vector_type(4))) float;

// width-1 spans: mb = state max; E = bf16(exp(unary - mb)) for terminal slots.
__global__ void unary_init(const float* __restrict__ unary,
                           float* __restrict__ mb, short* __restrict__ E){
  int k = blockIdx.x, b = blockIdx.y, j = threadIdx.x;
  float v = (j < T) ? unary[(b*N + k)*T + j] : NEGF;
  float m = v;
  #pragma unroll
  for (int off = 32; off > 0; off >>= 1) m = fmaxf(m, __shfl_xor(m, off));
  if (j == 0) mb[(b*NP1 + k)*NP1 + (k+1)] = m;
  if (j < T){
    __hip_bfloat16 h = __float2bfloat16(__expf(v - m));
    E[((b*NP1 + k)*NP1 + (k+1))*S + NT + j] = *reinterpret_cast<short*>(&h);
  }
}

// Vectorized 2-pass rule prep: float4 max pass; float2 -> 2 exps -> packed uint store.
__global__ __launch_bounds__(256) void rule_prep(const float* __restrict__ rule,
                                                 float* __restrict__ m_rule,
                                                 __hip_bfloat16* __restrict__ erule){
  int p = blockIdx.x, b = blockIdx.y, tid = threadIdx.x;
  size_t base = (size_t)(b*NT + p) * SS;
  size_t obase = (size_t)(b*NT + p) * KK;
  const float4* r4 = (const float4*)(rule + base);
  float lm = NEGF;
  for (int i = tid; i < SS/4; i += 256){
    float4 v = r4[i];
    lm = fmaxf(fmaxf(lm, fmaxf(v.x, v.y)), fmaxf(v.z, v.w));
  }
  #pragma unroll
  for (int off = 32; off > 0; off >>= 1) lm = fmaxf(lm, __shfl_xor(lm, off));
  __shared__ float wmax[4];
  __shared__ float sm;
  if ((tid & 63) == 0) wmax[tid >> 6] = lm;
  __syncthreads();
  if (tid == 0){
    float m = fmaxf(fmaxf(wmax[0], wmax[1]), fmaxf(wmax[2], wmax[3]));
    m_rule[b*NT + p] = m;
    sm = m;
  }
  __syncthreads();
  float m = sm;
  for (int idx = tid; idx < S * 48; idx += 256){
    int l = idx / 48, pr = idx - l * 48;
    int r = pr * 2;
    unsigned int out = 0;
    if (r < S){
      float2 v = *(const float2*)(rule + base + l*S + r);
      __hip_bfloat16 h0 = __float2bfloat16(__expf(v.x - m));
      __hip_bfloat16 h1 = __float2bfloat16(__expf(v.y - m));
      out = (unsigned int)*(unsigned short*)&h0 |
            ((unsigned int)*(unsigned short*)&h1 << 16);
    }
    *(unsigned int*)&erule[obase + l*KP + r] = out;
  }
}

// Per span (b,s) of width w: O[l,r] = sum_k el[k,l]*er[k,r] via MFMA.
// E-cache staging + child-width validity masks.
__global__ __launch_bounds__(256) void stage1(int w, const short* __restrict__ E,
                                              const float* __restrict__ mb,
                                              float* __restrict__ Mbuf,
                                              __hip_bfloat16* __restrict__ Og){
  int s = blockIdx.x, b = blockIdx.y, e = s + w, tid = threadIdx.x;
  int K = w - 1;
  int Kpad = (K + 31) & ~31;          // 32 or 64
  __shared__ float stmp[NSMAX];
  __shared__ float cK[NSMAX];
  __shared__ float sM;
  __shared__ __align__(16) short sbuf[2 * S1R * S1STR];  // 27.6 KB
  short* elT = sbuf;
  short* erT = sbuf + S1R * S1STR;

  if (tid < K){
    int u = s + tid + 1;
    stmp[tid] = mb[(b*NP1 + s)*NP1 + u] + mb[(b*NP1 + u)*NP1 + e];
  }
  __syncthreads();
  if (tid == 0){
    float M = NEGF;
    for (int k = 0; k < K; ++k) M = fmaxf(M, stmp[k]);
    sM = M;
    Mbuf[b*NSMAX + s] = M;
  }
  __syncthreads();
  float M = sM;
  if (tid < K) cK[tid] = __expf(stmp[tid] - M);
  __syncthreads();

  int items = S1R * Kpad;
  for (int idx = tid; idx < items; idx += 256){
    int k = idx / S1R, i = idx - k * S1R;   // i fastest -> coalesced E reads
    short ve = 0, vr = 0;
    if (i < S && k < K){
      int u = s + k + 1;
      // left child width = k+1; right child width = K-k. Width-1 cells hold
      // only terminal states (i>=NT); wider cells only nonterminals (i<NT).
      bool lOK = (k == 0)     ? (i >= NT) : (i < NT);
      bool rOK = (k == K - 1) ? (i >= NT) : (i < NT);
      if (lOK){
        unsigned short eL = (unsigned short)E[((b*NP1 + s)*NP1 + u)*S + i];
        float el = __uint_as_float((unsigned int)eL << 16) * cK[k];
        __hip_bfloat16 he = __float2bfloat16(el);
        ve = *reinterpret_cast<short*>(&he);
      }
      if (rOK) vr = E[((b*NP1 + u)*NP1 + e)*S + i];
    }
    elT[i*S1STR + k] = ve;
    erT[i*S1STR + k] = vr;
  }
  __syncthreads();

  int wid = tid >> 6, lane = tid & 63;
  int rr = lane & 15, hi = lane >> 4;
  int ksteps = Kpad >> 5;
  f32x4 accs[9];
  #pragma unroll
  for (int j = 0; j < 9; ++j){           // 36 tiles over 4 waves
    int t = wid * 9 + j;
    int tr = t / 6, tc = t - tr * 6;
    int ar = tr*16 + rr, br = tc*16 + rr;
    f32x4 acc = {0.f, 0.f, 0.f, 0.f};
    for (int ks = 0; ks < ksteps; ++ks){
      int kb = ks*32 + hi*8;
      bf16x8 af = *(bf16x8*)&elT[ar*S1STR + kb];
      bf16x8 bf2 = *(bf16x8*)&erT[br*S1STR + kb];
      acc = __builtin_amdgcn_mfma_f32_16x16x32_bf16(af, bf2, acc, 0, 0, 0);
    }
    accs[j] = acc;
  }
  __syncthreads();                        // all elT/erT reads done; sbuf reusable

  // repack: bf16 O tile, linear [l*96 + r] in sbuf, then coalesced 16B stores
  short* rep = sbuf;
  for (int idx = tid; idx < S * (KP - S); idx += 256){
    int l = idx / (KP - S), c = idx - l * (KP - S);
    rep[l*KP + S + c] = 0;
  }
  #pragma unroll
  for (int j = 0; j < 9; ++j){
    int t = wid * 9 + j;
    int tr = t / 6, tc = t - tr * 6;
    int rcol = tc*16 + rr;
    if (rcol < S){
      #pragma unroll
      for (int q = 0; q < 4; ++q){
        int l = tr*16 + hi*4 + q;
        if (l < S){
          __hip_bfloat16 h = __float2bfloat16(accs[j][q]);
          rep[l*KP + rcol] = *reinterpret_cast<short*>(&h);
        }
      }
    }
  }
  __syncthreads();

  size_t obase = ((size_t)(b*NSMAX + s)) * KK;
  uint4* dst = (uint4*)(Og + obase);
  const uint4* src = (const uint4*)rep;
  for (int i = tid; i < KK/8; i += 256) dst[i] = src[i];
}

// MFMA split-K GEMM (8 waves = 2 Mtiles x 4 Ntiles), single-barrier register
// double-buffer, 960 blocks. (R14 lesson: grid=64 full-K starves the machine.)
__global__ __launch_bounds__(512) void stage2(int ns, int ntiles,
                                              const __hip_bfloat16* __restrict__ erule,
                                              const __hip_bfloat16* __restrict__ Og,
                                              float* __restrict__ Cpart){
  int kc = blockIdx.x, b = blockIdx.y, tid = threadIdx.x;
  __shared__ __align__(16) short lds[2 * MTOT];   // 27.6 KB (dbuf)
  int wid = tid >> 6, lane = tid & 63;
  int mt = wid & 1, nt = wid >> 1;
  f32x4 acc = {0.f, 0.f, 0.f, 0.f};

  for (int i = tid; i < 2*MTOT; i += 512) lds[i] = 0;

  int slot = tid & 7;
  int aRow = (tid >> 3) & 31;                 // threads 0..255 -> A rows 0..31
  bool aDo = (tid < 256) && (aRow < NT);
  int bRow = tid >> 3;                        // 512 threads -> B rows 0..63
  bool bDo = bRow < ns;
  const __hip_bfloat16* aSrc = erule + ((size_t)(b*NT + (aDo ? aRow : 0))) * KK + slot * 8;
  const __hip_bfloat16* bSrc = Og    + ((size_t)(b*NSMAX + (bDo ? bRow : 0))) * KK + slot * 8;
  int aOff = aRow * MLSTR + slot * 8;
  int bOff = AOFFE + bRow * MLSTR + slot * 8;

  int arow = mt*16 + (lane & 15);
  int brow = nt*16 + (lane & 15);
  int hi = lane >> 4;
  bool active = nt < ntiles;
  int t0 = kc * TPC;

  uint4 ra, rb;
  if (aDo) ra = *(const uint4*)(aSrc + (size_t)t0 * KT2);
  if (bDo) rb = *(const uint4*)(bSrc + (size_t)t0 * KT2);
  __syncthreads();   // zero-fill complete before first data writes

  int cur = 0;
  for (int tt = 0; tt < TPC; ++tt){
    if (aDo) *(uint4*)&lds[cur*MTOT + aOff] = ra;
    if (bDo) *(uint4*)&lds[cur*MTOT + bOff] = rb;
    if (tt + 1 < TPC){
      size_t koff = (size_t)(t0 + tt + 1) * KT2;
      if (aDo) ra = *(const uint4*)(aSrc + koff);
      if (bDo) rb = *(const uint4*)(bSrc + koff);
    }
    __syncthreads();   // buf[cur] staged; compute(tt-1) on buf[cur^1] done
    if (active){
      #pragma unroll
      for (int ks = 0; ks < 2; ++ks){
        int sb = ks*4 + hi;
        bf16x8 af = *(bf16x8*)&lds[cur*MTOT + arow*MLSTR + sb*8];
        bf16x8 bf2 = *(bf16x8*)&lds[cur*MTOT + AOFFE + brow*MLSTR + sb*8];
        acc = __builtin_amdgcn_mfma_f32_16x16x32_bf16(af, bf2, acc, 0, 0, 0);
      }
    }
    cur ^= 1;
  }

  if (active){
    float* cp = Cpart + ((size_t)(kc*B + b)) * CELLS;
    int scol = nt*16 + (lane & 15);
    if (scol < ns){
      #pragma unroll
      for (int r = 0; r < 4; ++r){
        int p = mt*16 + hi*4 + r;
        if (p < NT) cp[p*ns + scol] = acc[r];
      }
    }
  }
}

// Linear-domain finalize: per-cell log/exp CANCEL.
// q = Csum*exp(m_rule); E = q/max_p q; mb = M + log(max_p q). No beta writes.
__global__ __launch_bounds__(256) void finalize(int w, int ns, const float* __restrict__ Cpart,
                                                const float* __restrict__ Mbuf,
                                                const float* __restrict__ m_rule,
                                                float* __restrict__ mb,
                                                short* __restrict__ E){
  int b = blockIdx.x, tid = threadIdx.x;
  __shared__ float q[CELLS];        // [si*NT + p]
  __shared__ float smax[NSMAX];
  __shared__ float emr[NT];
  if (tid < NT) emr[tid] = __expf(m_rule[b*NT + tid]);
  __syncthreads();
  for (int cell = tid; cell < NT * ns; cell += 256){
    int p = cell / ns, si = cell - p * ns;
    float sum = 0.f;
    #pragma unroll
    for (int kc = 0; kc < KSPL; ++kc) sum += Cpart[((size_t)(kc*B + b))*CELLS + cell];
    q[si*NT + p] = sum * emr[p];
  }
  __syncthreads();
  if (tid < ns){
    float m = 1e-37f;
    for (int p = 0; p < NT; ++p) m = fmaxf(m, q[tid*NT + p]);
    smax[tid] = m;
    mb[(b*NP1 + tid)*NP1 + (tid + w)] = Mbuf[b*NSMAX + tid] + __logf(m);
  }
  __syncthreads();
  for (int idx = tid; idx < ns * NT; idx += 256){
    int si = idx / NT, p = idx - si * NT;   // p fastest -> coalesced E writes
    __hip_bfloat16 h = __float2bfloat16(q[idx] / smax[si]);
    E[((b*NP1 + si)*NP1 + (si + w))*S + p] = *reinterpret_cast<short*>(&h);
  }
}

// Root: beta(w=50) computed directly from Cpart (ns=1: cell index = p).
__global__ void root_lse(const float* __restrict__ Cpart, const float* __restrict__ Mbuf,
                         const float* __restrict__ m_rule, const float* __restrict__ root,
                         float* __restrict__ out){
  int b = blockIdx.x, j = threadIdx.x;
  float v = NEGF;
  if (j < NT){
    float sum = 0.f;
    #pragma unroll
    for (int q = 0; q < KSPL; ++q)
      sum += Cpart[((size_t)(q*B + b))*CELLS + j];
    v = __logf(fmaxf(sum, 1e-37f)) + Mbuf[b*NSMAX + 0]
      + m_rule[b*NT + j] + root[b*NT + j];
  }
  float m = v;
  #pragma unroll
  for (int off = 32; off > 0; off >>= 1) m = fmaxf(m, __shfl_xor(m, off));
  float ex = __expf(v - m);
  #pragma unroll
  for (int off = 32; off > 0; off >>= 1) ex += __shfl_xor(ex, off);
  if (j == 0) out[b] = __logf(ex) + m;
}

} // namespace

extern "C" void kernel_launch(void* const* d_in, const int* in_sizes, int n_in,
                              void* d_out, int out_size, void* d_ws, size_t ws_size,
                              hipStream_t stream){
  (void)in_sizes; (void)n_in; (void)out_size; (void)ws_size;
  const float* unary = (const float*)d_in[0];
  const float* rule  = (const float*)d_in[1];
  const float* root  = (const float*)d_in[2];

  char* ws = (char*)d_ws;
  size_t off = 0;
  auto alloc = [&](size_t bytes) -> void* {
    void* p = ws + off;
    off += (bytes + 255) & ~(size_t)255;
    return p;
  };
  float* mb     = (float*)alloc(sizeof(float) * (size_t)B * NP1 * NP1);
  float* m_rule = (float*)alloc(sizeof(float) * B * NT);
  float* Mbuf   = (float*)alloc(sizeof(float) * B * NSMAX);
  float* Cpart  = (float*)alloc(sizeof(float) * KSPL * B * CELLS);   // 5.6 MB
  short* E      = (short*)alloc(sizeof(short) * (size_t)ECOUNT);     // 30 MB bf16
  __hip_bfloat16* erule = (__hip_bfloat16*)alloc(sizeof(__hip_bfloat16) * (size_t)B * NT * KK);
  __hip_bfloat16* Og    = (__hip_bfloat16*)alloc(sizeof(__hip_bfloat16) * (size_t)B * NSMAX * KK);

  unary_init<<<dim3(N, B), dim3(64), 0, stream>>>(unary, mb, E);
  rule_prep<<<dim3(NT, B), dim3(256), 0, stream>>>(rule, m_rule, erule);

  for (int w = 2; w <= N; ++w){
    int ns = N - w + 1;
    int ntiles = (ns + 15) >> 4;
    stage1<<<dim3(ns, B), dim3(256), 0, stream>>>(w, E, mb, Mbuf, Og);
    stage2<<<dim3(KSPL, B), dim3(512), 0, stream>>>(ns, ntiles, erule, Og, Cpart);
    if (w < N)
      finalize<<<dim3(B), dim3(256), 0, stream>>>(w, ns, Cpart, Mbuf, m_rule, mb, E);
  }
  root_lse<<<dim3(B), dim3(64), 0, stream>>>(Cpart, Mbuf, m_rule, root, (float*)d_out);
}

// Round 16
// 1624.042 us; speedup vs baseline: 2.1442x; 1.1002x over previous
//
#include <hip/hip_runtime.h>
#include <hip/hip_bf16.h>

#define NEGF (-1000000000.0f)

namespace {

constexpr int B  = 64;
constexpr int N  = 50;
constexpr int NT = 30;
constexpr int T  = 60;
constexpr int S  = 90;          // NT + T
constexpr int NP1 = N + 1;      // 51
constexpr int NSMAX = N - 1;    // 49
constexpr int SS = S * S;       // 8100
constexpr int CELLS = NT * NSMAX; // 1470
constexpr int ECOUNT = B * NP1 * NP1 * S;

// ---- padded K layout (now in BYTES: fp8 = 1 B/element) ----
constexpr int KP  = 96;          // padded r-dim per l (pads are exact 0)
constexpr int KK  = S * KP;      // 8640 elements = bytes
constexpr int KSPL = 15;         // split-K chunks
constexpr int KT2B = 64;         // K-tile: 64 k = 64 bytes per row slice
constexpr int NKT = KK / KT2B;   // 135
constexpr int TPC = NKT / KSPL;  // 9 tiles per chunk
constexpr int ROWB  = 72;        // stage2 LDS row stride in bytes (64 data + 8 pad)
constexpr int AOFFB = 32 * ROWB;              // B region byte offset
constexpr int MTOTB = (32 + 64) * ROWB;       // 6912 B per buffer

// ---- stage1 MFMA layout (bf16 internal) ----
constexpr int S1R = 96;          // padded state rows: 6 tiles of 16
constexpr int S1STR = 72;        // row stride in shorts (144B, b128-aligned)

using bf16x8 = __attribute__((ext_vector_type(8))) short;
using f32x4  = __attribute__((ext_vector_type(4))) float;

// pack 4 floats -> 4 e4m3 bytes (HW cvt)
__device__ __forceinline__ unsigned int pk4_e4m3(float a, float b, float c, float d){
  int w = __builtin_amdgcn_cvt_pk_fp8_f32(a, b, 0, false);
  w = __builtin_amdgcn_cvt_pk_fp8_f32(c, d, w, true);
  return (unsigned int)w;
}

// width-1 spans: mb = state max; E = bf16(exp(unary - mb)) for terminal slots.
__global__ void unary_init(const float* __restrict__ unary,
                           float* __restrict__ mb, short* __restrict__ E){
  int k = blockIdx.x, b = blockIdx.y, j = threadIdx.x;
  float v = (j < T) ? unary[(b*N + k)*T + j] : NEGF;
  float m = v;
  #pragma unroll
  for (int off = 32; off > 0; off >>= 1) m = fmaxf(m, __shfl_xor(m, off));
  if (j == 0) mb[(b*NP1 + k)*NP1 + (k+1)] = m;
  if (j < T){
    __hip_bfloat16 h = __float2bfloat16(__expf(v - m));
    E[((b*NP1 + k)*NP1 + (k+1))*S + NT + j] = *reinterpret_cast<short*>(&h);
  }
}

// 2-pass rule prep -> fp8 e4m3: float4 max pass; quad exp -> packed uint store.
__global__ __launch_bounds__(256) void rule_prep(const float* __restrict__ rule,
                                                 float* __restrict__ m_rule,
                                                 unsigned char* __restrict__ erule8){
  int p = blockIdx.x, b = blockIdx.y, tid = threadIdx.x;
  size_t base = (size_t)(b*NT + p) * SS;
  size_t obase = (size_t)(b*NT + p) * KK;
  const float4* r4 = (const float4*)(rule + base);
  float lm = NEGF;
  for (int i = tid; i < SS/4; i += 256){
    float4 v = r4[i];
    lm = fmaxf(fmaxf(lm, fmaxf(v.x, v.y)), fmaxf(v.z, v.w));
  }
  #pragma unroll
  for (int off = 32; off > 0; off >>= 1) lm = fmaxf(lm, __shfl_xor(lm, off));
  __shared__ float wmax[4];
  __shared__ float sm;
  if ((tid & 63) == 0) wmax[tid >> 6] = lm;
  __syncthreads();
  if (tid == 0){
    float m = fmaxf(fmaxf(wmax[0], wmax[1]), fmaxf(wmax[2], wmax[3]));
    m_rule[b*NT + p] = m;
    sm = m;
  }
  __syncthreads();
  float m = sm;
  // 24 r-quads per l (r>=90 pads -> 0)
  for (int idx = tid; idx < S * 24; idx += 256){
    int l = idx / 24, q4 = idx - l * 24;
    int r = q4 * 4;
    float e[4];
    #pragma unroll
    for (int j = 0; j < 4; ++j){
      int rr = r + j;
      e[j] = (rr < S) ? __expf(rule[base + l*S + rr] - m) : 0.f;
    }
    *(unsigned int*)&erule8[obase + l*KP + r] = pk4_e4m3(e[0], e[1], e[2], e[3]);
  }
}

// Per span (b,s) of width w: O[l,r] = sum_k el[k,l]*er[k,r] via bf16 MFMA,
// output converted to fp8 e4m3 via LDS repack + coalesced uint4 stores.
__global__ __launch_bounds__(256) void stage1(int w, const short* __restrict__ E,
                                              const float* __restrict__ mb,
                                              float* __restrict__ Mbuf,
                                              unsigned char* __restrict__ Og8){
  int s = blockIdx.x, b = blockIdx.y, e = s + w, tid = threadIdx.x;
  int K = w - 1;
  int Kpad = (K + 31) & ~31;          // 32 or 64
  __shared__ float stmp[NSMAX];
  __shared__ float cK[NSMAX];
  __shared__ float sM;
  __shared__ __align__(16) short sbuf[2 * S1R * S1STR];  // 27.6 KB
  short* elT = sbuf;
  short* erT = sbuf + S1R * S1STR;

  if (tid < K){
    int u = s + tid + 1;
    stmp[tid] = mb[(b*NP1 + s)*NP1 + u] + mb[(b*NP1 + u)*NP1 + e];
  }
  __syncthreads();
  if (tid == 0){
    float M = NEGF;
    for (int k = 0; k < K; ++k) M = fmaxf(M, stmp[k]);
    sM = M;
    Mbuf[b*NSMAX + s] = M;
  }
  __syncthreads();
  float M = sM;
  if (tid < K) cK[tid] = __expf(stmp[tid] - M);
  __syncthreads();

  int items = S1R * Kpad;
  for (int idx = tid; idx < items; idx += 256){
    int k = idx / S1R, i = idx - k * S1R;   // i fastest -> coalesced E reads
    short ve = 0, vr = 0;
    if (i < S && k < K){
      int u = s + k + 1;
      // left child width = k+1; right child width = K-k. Width-1 cells hold
      // only terminal states (i>=NT); wider cells only nonterminals (i<NT).
      bool lOK = (k == 0)     ? (i >= NT) : (i < NT);
      bool rOK = (k == K - 1) ? (i >= NT) : (i < NT);
      if (lOK){
        unsigned short eL = (unsigned short)E[((b*NP1 + s)*NP1 + u)*S + i];
        float el = __uint_as_float((unsigned int)eL << 16) * cK[k];
        __hip_bfloat16 he = __float2bfloat16(el);
        ve = *reinterpret_cast<short*>(&he);
      }
      if (rOK) vr = E[((b*NP1 + u)*NP1 + e)*S + i];
    }
    elT[i*S1STR + k] = ve;
    erT[i*S1STR + k] = vr;
  }
  __syncthreads();

  int wid = tid >> 6, lane = tid & 63;
  int rr = lane & 15, hi = lane >> 4;
  int ksteps = Kpad >> 5;
  f32x4 accs[9];
  #pragma unroll
  for (int j = 0; j < 9; ++j){           // 36 tiles over 4 waves
    int t = wid * 9 + j;
    int tr = t / 6, tc = t - tr * 6;
    int ar = tr*16 + rr, br = tc*16 + rr;
    f32x4 acc = {0.f, 0.f, 0.f, 0.f};
    for (int ks = 0; ks < ksteps; ++ks){
      int kb = ks*32 + hi*8;
      bf16x8 af = *(bf16x8*)&elT[ar*S1STR + kb];
      bf16x8 bf2 = *(bf16x8*)&erT[br*S1STR + kb];
      acc = __builtin_amdgcn_mfma_f32_16x16x32_bf16(af, bf2, acc, 0, 0, 0);
    }
    accs[j] = acc;
  }
  __syncthreads();                        // all elT/erT reads done; sbuf reusable

  // repack: fp8 O tile, linear [l*96 + r] bytes in sbuf, then uint4 stores
  unsigned char* rep = (unsigned char*)sbuf;
  for (int idx = tid; idx < S * (KP - S); idx += 256){
    int l = idx / (KP - S), c = idx - l * (KP - S);
    rep[l*KP + S + c] = 0;
  }
  #pragma unroll
  for (int j = 0; j < 9; ++j){
    int t = wid * 9 + j;
    int tr = t / 6, tc = t - tr * 6;
    int rcol = tc*16 + rr;
    if (rcol < S){
      unsigned int pk = pk4_e4m3(accs[j][0], accs[j][1], accs[j][2], accs[j][3]);
      #pragma unroll
      for (int q = 0; q < 4; ++q){
        int l = tr*16 + hi*4 + q;
        if (l < S) rep[l*KP + rcol] = (unsigned char)((pk >> (8*q)) & 0xff);
      }
    }
  }
  __syncthreads();

  size_t obase = ((size_t)(b*NSMAX + s)) * KK;
  uint4* dst = (uint4*)(Og8 + obase);
  const uint4* src = (const uint4*)rep;
  for (int i = tid; i < KK/16; i += 256) dst[i] = src[i];   // 540 coalesced 16B stores
}

// fp8 MFMA split-K GEMM (8 waves = 2 Mtiles x 4 Ntiles), single-barrier register
// double-buffer, 960 blocks. A/B loaded with IDENTICAL per-lane patterns ->
// any intra-fragment k-permutation cancels in the contraction (layout-safe).
__global__ __launch_bounds__(512) void stage2(int ns, int ntiles,
                                              const unsigned char* __restrict__ erule8,
                                              const unsigned char* __restrict__ Og8,
                                              float* __restrict__ Cpart){
  int kc = blockIdx.x, b = blockIdx.y, tid = threadIdx.x;
  __shared__ __align__(16) unsigned char ldsb[2 * MTOTB];   // 13.8 KB (dbuf)
  int wid = tid >> 6, lane = tid & 63;
  int mt = wid & 1, nt = wid >> 1;
  f32x4 acc = {0.f, 0.f, 0.f, 0.f};

  for (int i = tid; i < 2*MTOTB/4; i += 512) ((unsigned int*)ldsb)[i] = 0;

  int slot = tid & 7;
  int aRow = (tid >> 3) & 31;                 // threads 0..255 -> A rows 0..31
  bool aDo = (tid < 256) && (aRow < NT);
  int bRow = tid >> 3;                        // 512 threads -> B rows 0..63
  bool bDo = bRow < ns;
  const unsigned char* aSrc = erule8 + ((size_t)(b*NT + (aDo ? aRow : 0))) * KK + slot * 8;
  const unsigned char* bSrc = Og8    + ((size_t)(b*NSMAX + (bDo ? bRow : 0))) * KK + slot * 8;
  int aOff = aRow * ROWB + slot * 8;
  int bOff = AOFFB + bRow * ROWB + slot * 8;

  int arow = mt*16 + (lane & 15);
  int brow = nt*16 + (lane & 15);
  int hi = lane >> 4;
  bool active = nt < ntiles;
  int t0 = kc * TPC;

  uint2 ra, rb;
  if (aDo) ra = *(const uint2*)(aSrc + (size_t)t0 * KT2B);
  if (bDo) rb = *(const uint2*)(bSrc + (size_t)t0 * KT2B);
  __syncthreads();   // zero-fill complete before first data writes

  int cur = 0;
  for (int tt = 0; tt < TPC; ++tt){
    if (aDo) *(uint2*)&ldsb[cur*MTOTB + aOff] = ra;
    if (bDo) *(uint2*)&ldsb[cur*MTOTB + bOff] = rb;
    if (tt + 1 < TPC){
      size_t koff = (size_t)(t0 + tt + 1) * KT2B;
      if (aDo) ra = *(const uint2*)(aSrc + koff);
      if (bDo) rb = *(const uint2*)(bSrc + koff);
    }
    __syncthreads();   // buf[cur] staged; compute(tt-1) on buf[cur^1] done
    if (active){
      #pragma unroll
      for (int ks = 0; ks < 2; ++ks){
        int sb = ks*4 + hi;
        long af = *(const long*)&ldsb[cur*MTOTB + arow*ROWB + sb*8];
        long bf2 = *(const long*)&ldsb[cur*MTOTB + AOFFB + brow*ROWB + sb*8];
        acc = __builtin_amdgcn_mfma_f32_16x16x32_fp8_fp8(af, bf2, acc, 0, 0, 0);
      }
    }
    cur ^= 1;
  }

  if (active){
    float* cp = Cpart + ((size_t)(kc*B + b)) * CELLS;
    int scol = nt*16 + (lane & 15);
    if (scol < ns){
      #pragma unroll
      for (int r = 0; r < 4; ++r){
        int p = mt*16 + hi*4 + r;
        if (p < NT) cp[p*ns + scol] = acc[r];
      }
    }
  }
}

// Linear-domain finalize: q = Csum*exp(m_rule); E = q/max; mb = M + log(max).
__global__ __launch_bounds__(256) void finalize(int w, int ns, const float* __restrict__ Cpart,
                                                const float* __restrict__ Mbuf,
                                                const float* __restrict__ m_rule,
                                                float* __restrict__ mb,
                                                short* __restrict__ E){
  int b = blockIdx.x, tid = threadIdx.x;
  __shared__ float q[CELLS];        // [si*NT + p]
  __shared__ float smax[NSMAX];
  __shared__ float emr[NT];
  if (tid < NT) emr[tid] = __expf(m_rule[b*NT + tid]);
  __syncthreads();
  for (int cell = tid; cell < NT * ns; cell += 256){
    int p = cell / ns, si = cell - p * ns;
    float sum = 0.f;
    #pragma unroll
    for (int kc = 0; kc < KSPL; ++kc) sum += Cpart[((size_t)(kc*B + b))*CELLS + cell];
    q[si*NT + p] = sum * emr[p];
  }
  __syncthreads();
  if (tid < ns){
    float m = 1e-37f;
    for (int p = 0; p < NT; ++p) m = fmaxf(m, q[tid*NT + p]);
    smax[tid] = m;
    mb[(b*NP1 + tid)*NP1 + (tid + w)] = Mbuf[b*NSMAX + tid] + __logf(m);
  }
  __syncthreads();
  for (int idx = tid; idx < ns * NT; idx += 256){
    int si = idx / NT, p = idx - si * NT;
    __hip_bfloat16 h = __float2bfloat16(q[idx] / smax[si]);
    E[((b*NP1 + si)*NP1 + (si + w))*S + p] = *reinterpret_cast<short*>(&h);
  }
}

// Root: beta(w=50) computed directly from Cpart (ns=1: cell index = p).
__global__ void root_lse(const float* __restrict__ Cpart, const float* __restrict__ Mbuf,
                         const float* __restrict__ m_rule, const float* __restrict__ root,
                         float* __restrict__ out){
  int b = blockIdx.x, j = threadIdx.x;
  float v = NEGF;
  if (j < NT){
    float sum = 0.f;
    #pragma unroll
    for (int q = 0; q < KSPL; ++q)
      sum += Cpart[((size_t)(q*B + b))*CELLS + j];
    v = __logf(fmaxf(sum, 1e-37f)) + Mbuf[b*NSMAX + 0]
      + m_rule[b*NT + j] + root[b*NT + j];
  }
  float m = v;
  #pragma unroll
  for (int off = 32; off > 0; off >>= 1) m = fmaxf(m, __shfl_xor(m, off));
  float ex = __expf(v - m);
  #pragma unroll
  for (int off = 32; off > 0; off >>= 1) ex += __shfl_xor(ex, off);
  if (j == 0) out[b] = __logf(ex) + m;
}

} // namespace

extern "C" void kernel_launch(void* const* d_in, const int* in_sizes, int n_in,
                              void* d_out, int out_size, void* d_ws, size_t ws_size,
                              hipStream_t stream){
  (void)in_sizes; (void)n_in; (void)out_size; (void)ws_size;
  const float* unary = (const float*)d_in[0];
  const float* rule  = (const float*)d_in[1];
  const float* root  = (const float*)d_in[2];

  char* ws = (char*)d_ws;
  size_t off = 0;
  auto alloc = [&](size_t bytes) -> void* {
    void* p = ws + off;
    off += (bytes + 255) & ~(size_t)255;
    return p;
  };
  float* mb     = (float*)alloc(sizeof(float) * (size_t)B * NP1 * NP1);
  float* m_rule = (float*)alloc(sizeof(float) * B * NT);
  float* Mbuf   = (float*)alloc(sizeof(float) * B * NSMAX);
  float* Cpart  = (float*)alloc(sizeof(float) * KSPL * B * CELLS);   // 5.6 MB
  short* E      = (short*)alloc(sizeof(short) * (size_t)ECOUNT);     // 30 MB bf16
  unsigned char* erule8 = (unsigned char*)alloc((size_t)B * NT * KK);    // 16.6 MB fp8
  unsigned char* Og8    = (unsigned char*)alloc((size_t)B * NSMAX * KK); // 27.1 MB fp8

  unary_init<<<dim3(N, B), dim3(64), 0, stream>>>(unary, mb, E);
  rule_prep<<<dim3(NT, B), dim3(256), 0, stream>>>(rule, m_rule, erule8);

  for (int w = 2; w <= N; ++w){
    int ns = N - w + 1;
    int ntiles = (ns + 15) >> 4;
    stage1<<<dim3(ns, B), dim3(256), 0, stream>>>(w, E, mb, Mbuf, Og8);
    stage2<<<dim3(KSPL, B), dim3(512), 0, stream>>>(ns, ntiles, erule8, Og8, Cpart);
    if (w < N)
      finalize<<<dim3(B), dim3(256), 0, stream>>>(w, ns, Cpart, Mbuf, m_rule, mb, E);
  }
  root_lse<<<dim3(B), dim3(64), 0, stream>>>(Cpart, Mbuf, m_rule, root, (float*)d_out);
}

// Round 17
// 1543.171 us; speedup vs baseline: 2.2566x; 1.0524x over previous
//
#include <hip/hip_runtime.h>
#include <hip/hip_bf16.h>

#define NEGF (-1000000000.0f)

namespace {

constexpr int B  = 64;
constexpr int N  = 50;
constexpr int NT = 30;
constexpr int T  = 60;
constexpr int S  = 90;          // NT + T
constexpr int NP1 = N + 1;      // 51
constexpr int NSMAX = N - 1;    // 49
constexpr int SS = S * S;       // 8100
constexpr int CELLSP = NSMAX * 32 + 32;  // padded cells (stride 32 per span)
constexpr int ECOUNT = B * NP1 * NP1 * S;

// ---- padded K layout (BYTES: fp8 = 1 B/element) ----
constexpr int KP  = 96;          // padded r-dim per l (pads are exact 0)
constexpr int KK  = S * KP;      // 8640 elements = bytes
constexpr int KSPL = 15;         // split-K chunks
constexpr int KT2B = 64;         // K-tile bytes per row slice
constexpr int NKT = KK / KT2B;   // 135
constexpr int TPC = NKT / KSPL;  // 9 tiles per chunk
constexpr int ROWB  = 72;        // stage2 LDS row stride bytes
constexpr int AOFFB = 32 * ROWB;
constexpr int MTOTB = (32 + 64) * ROWB;       // 6912 B per buffer

// ---- stage1 MFMA layout (bf16 internal) ----
constexpr int S1R = 96;          // padded state rows: 6 tiles of 16
constexpr int S1STR = 72;        // row stride in shorts (144B, b128-aligned)

using bf16x8 = __attribute__((ext_vector_type(8))) short;
using f32x4  = __attribute__((ext_vector_type(4))) float;

__device__ __forceinline__ unsigned int pk4_e4m3(float a, float b, float c, float d){
  int w = __builtin_amdgcn_cvt_pk_fp8_f32(a, b, 0, false);
  w = __builtin_amdgcn_cvt_pk_fp8_f32(c, d, w, true);
  return (unsigned int)w;
}

// width-1 spans: mb = state max; E_L/E_R = bf16(exp(unary - mb)) terminal slots.
__global__ void unary_init(const float* __restrict__ unary, float* __restrict__ mb,
                           short* __restrict__ E_L, short* __restrict__ E_R){
  int k = blockIdx.x, b = blockIdx.y, j = threadIdx.x;
  float v = (j < T) ? unary[(b*N + k)*T + j] : NEGF;
  float m = v;
  #pragma unroll
  for (int off = 32; off > 0; off >>= 1) m = fmaxf(m, __shfl_xor(m, off));
  if (j == 0) mb[(b*NP1 + k)*NP1 + (k+1)] = m;
  if (j < T){
    __hip_bfloat16 h = __float2bfloat16(__expf(v - m));
    short sv = *reinterpret_cast<short*>(&h);
    E_L[((size_t)((b*NP1 + k)*NP1 + (k+1)))*S + NT + j] = sv;
    E_R[((size_t)((b*NP1 + (k+1))*NP1 + k))*S + NT + j] = sv;
  }
}

// 2-pass rule prep -> fp8 e4m3.
__global__ __launch_bounds__(256) void rule_prep(const float* __restrict__ rule,
                                                 float* __restrict__ m_rule,
                                                 unsigned char* __restrict__ erule8){
  int p = blockIdx.x, b = blockIdx.y, tid = threadIdx.x;
  size_t base = (size_t)(b*NT + p) * SS;
  size_t obase = (size_t)(b*NT + p) * KK;
  const float4* r4 = (const float4*)(rule + base);
  float lm = NEGF;
  for (int i = tid; i < SS/4; i += 256){
    float4 v = r4[i];
    lm = fmaxf(fmaxf(lm, fmaxf(v.x, v.y)), fmaxf(v.z, v.w));
  }
  #pragma unroll
  for (int off = 32; off > 0; off >>= 1) lm = fmaxf(lm, __shfl_xor(lm, off));
  __shared__ float wmax[4];
  __shared__ float sm;
  if ((tid & 63) == 0) wmax[tid >> 6] = lm;
  __syncthreads();
  if (tid == 0){
    float m = fmaxf(fmaxf(wmax[0], wmax[1]), fmaxf(wmax[2], wmax[3]));
    m_rule[b*NT + p] = m;
    sm = m;
  }
  __syncthreads();
  float m = sm;
  for (int idx = tid; idx < S * 24; idx += 256){
    int l = idx / 24, q4 = idx - l * 24;
    int r = q4 * 4;
    float e[4];
    #pragma unroll
    for (int j = 0; j < 4; ++j){
      int rr = r + j;
      e[j] = (rr < S) ? __expf(rule[base + l*S + rr] - m) : 0.f;
    }
    *(unsigned int*)&erule8[obase + l*KP + r] = pk4_e4m3(e[0], e[1], e[2], e[3]);
  }
}

// Per span (b,s) of width w: O[l,r] = sum_k el[k,l]*er[k,r] via bf16 MFMA.
// R17: both child gathers contiguous (E_L + E_R layouts), uint-vectorized.
__global__ __launch_bounds__(256) void stage1(int w, const short* __restrict__ E_L,
                                              const short* __restrict__ E_R,
                                              const float* __restrict__ mb,
                                              float* __restrict__ Mbuf,
                                              unsigned char* __restrict__ Og8){
  int s = blockIdx.x, b = blockIdx.y, e = s + w, tid = threadIdx.x;
  int K = w - 1;
  int Kpad = (K + 31) & ~31;          // 32 or 64
  __shared__ float stmp[NSMAX];
  __shared__ float cK[NSMAX];
  __shared__ float sM;
  __shared__ __align__(16) short sbuf[2 * S1R * S1STR];  // 27.6 KB
  short* elT = sbuf;
  short* erT = sbuf + S1R * S1STR;

  if (tid < K){
    int u = s + tid + 1;
    stmp[tid] = mb[(b*NP1 + s)*NP1 + u] + mb[(b*NP1 + u)*NP1 + e];
  }
  __syncthreads();
  if (tid == 0){
    float M = NEGF;
    for (int k = 0; k < K; ++k) M = fmaxf(M, stmp[k]);
    sM = M;
    Mbuf[b*NSMAX + s] = M;
  }
  __syncthreads();
  float M = sM;
  if (tid < K) cK[tid] = __expf(stmp[tid] - M);
  __syncthreads();

  // contiguous bases: left children rows (s,u) u=s+1..s+K; right rows (u,e)
  const short* baseL = E_L + ((size_t)((b*NP1 + s)*NP1 + s + 1)) * S;
  const short* baseR = E_R + ((size_t)((b*NP1 + e)*NP1 + s + 1)) * S;

  int items = Kpad * 48;               // 48 uint pairs per k (45 data + 3 pad)
  for (int idx = tid; idx < items; idx += 256){
    int k = idx / 48, j = idx - k * 48;
    int i = 2 * j;
    short v0 = 0, v1 = 0, r0 = 0, r1 = 0;
    if (k < K && j < 45){
      // pair j<15 -> i<30 (nonterminals); j>=15 -> i>=30 (terminals)
      bool lOK = (k == 0)     ? (j >= 15) : (j < 15);
      bool rOK = (k == K - 1) ? (j >= 15) : (j < 15);
      if (lOK){
        unsigned int L = *(const unsigned int*)(baseL + k*S + i);
        float f0 = __uint_as_float(L << 16) * cK[k];
        float f1 = __uint_as_float(L & 0xFFFF0000u) * cK[k];
        __hip_bfloat16 h0 = __float2bfloat16(f0), h1 = __float2bfloat16(f1);
        v0 = *reinterpret_cast<short*>(&h0);
        v1 = *reinterpret_cast<short*>(&h1);
      }
      if (rOK){
        unsigned int R = *(const unsigned int*)(baseR + k*S + i);
        r0 = (short)(R & 0xFFFFu);
        r1 = (short)(R >> 16);
      }
    }
    elT[i*S1STR + k]     = v0;
    elT[(i+1)*S1STR + k] = v1;
    erT[i*S1STR + k]     = r0;
    erT[(i+1)*S1STR + k] = r1;
  }
  __syncthreads();

  int wid = tid >> 6, lane = tid & 63;
  int rr = lane & 15, hi = lane >> 4;
  int ksteps = Kpad >> 5;
  f32x4 accs[9];
  #pragma unroll
  for (int j = 0; j < 9; ++j){           // 36 tiles over 4 waves
    int t = wid * 9 + j;
    int tr = t / 6, tc = t - tr * 6;
    int ar = tr*16 + rr, br = tc*16 + rr;
    f32x4 acc = {0.f, 0.f, 0.f, 0.f};
    for (int ks = 0; ks < ksteps; ++ks){
      int kb = ks*32 + hi*8;
      bf16x8 af = *(bf16x8*)&elT[ar*S1STR + kb];
      bf16x8 bf2 = *(bf16x8*)&erT[br*S1STR + kb];
      acc = __builtin_amdgcn_mfma_f32_16x16x32_bf16(af, bf2, acc, 0, 0, 0);
    }
    accs[j] = acc;
  }
  __syncthreads();                        // all elT/erT reads done; sbuf reusable

  // repack: fp8 O tile, linear [l*96 + r] bytes in sbuf, then uint4 stores
  unsigned char* rep = (unsigned char*)sbuf;
  for (int idx = tid; idx < S * (KP - S); idx += 256){
    int l = idx / (KP - S), c = idx - l * (KP - S);
    rep[l*KP + S + c] = 0;
  }
  #pragma unroll
  for (int j = 0; j < 9; ++j){
    int t = wid * 9 + j;
    int tr = t / 6, tc = t - tr * 6;
    int rcol = tc*16 + rr;
    if (rcol < S){
      unsigned int pk = pk4_e4m3(accs[j][0], accs[j][1], accs[j][2], accs[j][3]);
      #pragma unroll
      for (int q = 0; q < 4; ++q){
        int l = tr*16 + hi*4 + q;
        if (l < S) rep[l*KP + rcol] = (unsigned char)((pk >> (8*q)) & 0xff);
      }
    }
  }
  __syncthreads();

  size_t obase = ((size_t)(b*NSMAX + s)) * KK;
  uint4* dst = (uint4*)(Og8 + obase);
  const uint4* src = (const uint4*)rep;
  for (int i = tid; i < KK/16; i += 256) dst[i] = src[i];
}

// fp8 MFMA split-K GEMM; Cpart cell layout [s*32 + p] -> one float4 store/lane.
__global__ __launch_bounds__(512) void stage2(int ns, int ntiles,
                                              const unsigned char* __restrict__ erule8,
                                              const unsigned char* __restrict__ Og8,
                                              float* __restrict__ Cpart){
  int kc = blockIdx.x, b = blockIdx.y, tid = threadIdx.x;
  __shared__ __align__(16) unsigned char ldsb[2 * MTOTB];   // 13.8 KB (dbuf)
  int wid = tid >> 6, lane = tid & 63;
  int mt = wid & 1, nt = wid >> 1;
  f32x4 acc = {0.f, 0.f, 0.f, 0.f};

  for (int i = tid; i < 2*MTOTB/4; i += 512) ((unsigned int*)ldsb)[i] = 0;

  int slot = tid & 7;
  int aRow = (tid >> 3) & 31;
  bool aDo = (tid < 256) && (aRow < NT);
  int bRow = tid >> 3;
  bool bDo = bRow < ns;
  const unsigned char* aSrc = erule8 + ((size_t)(b*NT + (aDo ? aRow : 0))) * KK + slot * 8;
  const unsigned char* bSrc = Og8    + ((size_t)(b*NSMAX + (bDo ? bRow : 0))) * KK + slot * 8;
  int aOff = aRow * ROWB + slot * 8;
  int bOff = AOFFB + bRow * ROWB + slot * 8;

  int arow = mt*16 + (lane & 15);
  int brow = nt*16 + (lane & 15);
  int hi = lane >> 4;
  bool active = nt < ntiles;
  int t0 = kc * TPC;

  uint2 ra, rb;
  if (aDo) ra = *(const uint2*)(aSrc + (size_t)t0 * KT2B);
  if (bDo) rb = *(const uint2*)(bSrc + (size_t)t0 * KT2B);
  __syncthreads();

  int cur = 0;
  for (int tt = 0; tt < TPC; ++tt){
    if (aDo) *(uint2*)&ldsb[cur*MTOTB + aOff] = ra;
    if (bDo) *(uint2*)&ldsb[cur*MTOTB + bOff] = rb;
    if (tt + 1 < TPC){
      size_t koff = (size_t)(t0 + tt + 1) * KT2B;
      if (aDo) ra = *(const uint2*)(aSrc + koff);
      if (bDo) rb = *(const uint2*)(bSrc + koff);
    }
    __syncthreads();
    if (active){
      #pragma unroll
      for (int ks = 0; ks < 2; ++ks){
        int sb = ks*4 + hi;
        long af = *(const long*)&ldsb[cur*MTOTB + arow*ROWB + sb*8];
        long bf2 = *(const long*)&ldsb[cur*MTOTB + AOFFB + brow*ROWB + sb*8];
        acc = __builtin_amdgcn_mfma_f32_16x16x32_fp8_fp8(af, bf2, acc, 0, 0, 0);
      }
    }
    cur ^= 1;
  }

  if (active){
    int scol = nt*16 + (lane & 15);
    if (scol < ns){
      int p0 = mt*16 + hi*4;           // acc[r] -> p = p0 + r (contiguous)
      float* cp = Cpart + ((size_t)(kc*B + b)) * CELLSP + scol*32 + p0;
      *(f32x4*)cp = acc;               // aligned (32-stride, p0 mult of 4);
                                       // p=30,31 overflow lands in padding
    }
  }
}

// Per-span finalize: grid (ns, B) x 64 threads; linear domain (log/exp cancel).
__global__ __launch_bounds__(64) void finalize(int w, const float* __restrict__ Cpart,
                                               const float* __restrict__ Mbuf,
                                               const float* __restrict__ m_rule,
                                               float* __restrict__ mb,
                                               short* __restrict__ E_L,
                                               short* __restrict__ E_R){
  int sp = blockIdx.x, b = blockIdx.y, tid = threadIdx.x;
  __shared__ float qs[32];
  float q = 1e-37f;
  if (tid < NT){
    float sum = 0.f;
    #pragma unroll
    for (int kc = 0; kc < KSPL; ++kc)
      sum += Cpart[((size_t)(kc*B + b))*CELLSP + sp*32 + tid];
    q = sum * __expf(m_rule[b*NT + tid]);
    qs[tid] = q;
  }
  float m = (tid < NT) ? q : 1e-37f;
  #pragma unroll
  for (int off = 32; off > 0; off >>= 1) m = fmaxf(m, __shfl_xor(m, off));
  m = fmaxf(m, 1e-37f);
  __syncthreads();
  if (tid == 0) mb[(b*NP1 + sp)*NP1 + (sp + w)] = Mbuf[b*NSMAX + sp] + __logf(m);
  if (tid < 15){
    float e0 = qs[2*tid] / m, e1 = qs[2*tid + 1] / m;
    __hip_bfloat16 h0 = __float2bfloat16(e0), h1 = __float2bfloat16(e1);
    unsigned int pk = (unsigned int)*(unsigned short*)&h0 |
                      ((unsigned int)*(unsigned short*)&h1 << 16);
    *(unsigned int*)&E_L[((size_t)((b*NP1 + sp)*NP1 + sp + w))*S + 2*tid] = pk;
    *(unsigned int*)&E_R[((size_t)((b*NP1 + sp + w)*NP1 + sp))*S + 2*tid] = pk;
  }
}

// Root: beta(w=50) computed directly from Cpart (ns=1: cell = p).
__global__ void root_lse(const float* __restrict__ Cpart, const float* __restrict__ Mbuf,
                         const float* __restrict__ m_rule, const float* __restrict__ root,
                         float* __restrict__ out){
  int b = blockIdx.x, j = threadIdx.x;
  float v = NEGF;
  if (j < NT){
    float sum = 0.f;
    #pragma unroll
    for (int q = 0; q < KSPL; ++q)
      sum += Cpart[((size_t)(q*B + b))*CELLSP + j];
    v = __logf(fmaxf(sum, 1e-37f)) + Mbuf[b*NSMAX + 0]
      + m_rule[b*NT + j] + root[b*NT + j];
  }
  float m = v;
  #pragma unroll
  for (int off = 32; off > 0; off >>= 1) m = fmaxf(m, __shfl_xor(m, off));
  float ex = __expf(v - m);
  #pragma unroll
  for (int off = 32; off > 0; off >>= 1) ex += __shfl_xor(ex, off);
  if (j == 0) out[b] = __logf(ex) + m;
}

} // namespace

extern "C" void kernel_launch(void* const* d_in, const int* in_sizes, int n_in,
                              void* d_out, int out_size, void* d_ws, size_t ws_size,
                              hipStream_t stream){
  (void)in_sizes; (void)n_in; (void)out_size; (void)ws_size;
  const float* unary = (const float*)d_in[0];
  const float* rule  = (const float*)d_in[1];
  const float* root  = (const float*)d_in[2];

  char* ws = (char*)d_ws;
  size_t off = 0;
  auto alloc = [&](size_t bytes) -> void* {
    void* p = ws + off;
    off += (bytes + 255) & ~(size_t)255;
    return p;
  };
  float* mb     = (float*)alloc(sizeof(float) * (size_t)B * NP1 * NP1);
  float* m_rule = (float*)alloc(sizeof(float) * B * NT);
  float* Mbuf   = (float*)alloc(sizeof(float) * B * NSMAX);
  float* Cpart  = (float*)alloc(sizeof(float) * KSPL * B * CELLSP);  // 6.1 MB
  short* E_L    = (short*)alloc(sizeof(short) * (size_t)ECOUNT);     // 30 MB
  short* E_R    = (short*)alloc(sizeof(short) * (size_t)ECOUNT);     // 30 MB
  unsigned char* erule8 = (unsigned char*)alloc((size_t)B * NT * KK);    // 16.6 MB
  unsigned char* Og8    = (unsigned char*)alloc((size_t)B * NSMAX * KK); // 27.1 MB

  unary_init<<<dim3(N, B), dim3(64), 0, stream>>>(unary, mb, E_L, E_R);
  rule_prep<<<dim3(NT, B), dim3(256), 0, stream>>>(rule, m_rule, erule8);

  for (int w = 2; w <= N; ++w){
    int ns = N - w + 1;
    int ntiles = (ns + 15) >> 4;
    stage1<<<dim3(ns, B), dim3(256), 0, stream>>>(w, E_L, E_R, mb, Mbuf, Og8);
    stage2<<<dim3(KSPL, B), dim3(512), 0, stream>>>(ns, ntiles, erule8, Og8, Cpart);
    if (w < N)
      finalize<<<dim3(ns, B), dim3(64), 0, stream>>>(w, Cpart, Mbuf, m_rule, mb, E_L, E_R);
  }
  root_lse<<<dim3(B), dim3(64), 0, stream>>>(Cpart, Mbuf, m_rule, root, (float*)d_out);
}

// Round 18
// 1526.174 us; speedup vs baseline: 2.2817x; 1.0111x over previous
//
#include <hip/hip_runtime.h>
#include <hip/hip_bf16.h>

#define NEGF (-1000000000.0f)

namespace {

constexpr int B  = 64;
constexpr int N  = 50;
constexpr int NT = 30;
constexpr int T  = 60;
constexpr int S  = 90;          // NT + T
constexpr int NP1 = N + 1;      // 51
constexpr int NSMAX = N - 1;    // 49
constexpr int SS = S * S;       // 8100
constexpr int CELLSP = NSMAX * 32 + 32;  // padded cells (stride 32 per span)
constexpr int ECOUNT = B * NP1 * NP1 * S;

// ---- padded K layout (BYTES: fp8 = 1 B/element) ----
constexpr int KP  = 96;          // padded r-dim per l (pads are exact 0)
constexpr int KK  = S * KP;      // 8640 elements = bytes
constexpr int KSPL = 15;         // split-K chunks
constexpr int KT2B = 64;         // K-tile bytes per row slice
constexpr int NKT = KK / KT2B;   // 135
constexpr int TPC = NKT / KSPL;  // 9 tiles per chunk
constexpr int ROWB  = 72;        // stage2 LDS row stride bytes
constexpr int AOFFB = 32 * ROWB;
constexpr int MTOTB = (32 + 64) * ROWB;       // 6912 B per buffer

// ---- stage1 MFMA layout (bf16 internal) ----
constexpr int S1R = 96;          // padded state rows: 6 tiles of 16
constexpr int S1STR = 72;        // row stride in shorts (144B, b128-aligned)

using bf16x8 = __attribute__((ext_vector_type(8))) short;
using f32x4  = __attribute__((ext_vector_type(4))) float;

__device__ __forceinline__ unsigned int pk4_e4m3(float a, float b, float c, float d){
  int w = __builtin_amdgcn_cvt_pk_fp8_f32(a, b, 0, false);
  w = __builtin_amdgcn_cvt_pk_fp8_f32(c, d, w, true);
  return (unsigned int)w;
}
__device__ __forceinline__ short f2bs(float v){
  __hip_bfloat16 h = __float2bfloat16(v);
  return *reinterpret_cast<short*>(&h);
}

// width-1 spans: mb = state max; E_L/E_R = bf16(exp(unary - mb)) terminal slots.
__global__ void unary_init(const float* __restrict__ unary, float* __restrict__ mb,
                           short* __restrict__ E_L, short* __restrict__ E_R){
  int k = blockIdx.x, b = blockIdx.y, j = threadIdx.x;
  float v = (j < T) ? unary[(b*N + k)*T + j] : NEGF;
  float m = v;
  #pragma unroll
  for (int off = 32; off > 0; off >>= 1) m = fmaxf(m, __shfl_xor(m, off));
  if (j == 0) mb[(b*NP1 + k)*NP1 + (k+1)] = m;
  if (j < T){
    short sv = f2bs(__expf(v - m));
    E_L[((size_t)((b*NP1 + k)*NP1 + (k+1)))*S + NT + j] = sv;
    E_R[((size_t)((b*NP1 + (k+1))*NP1 + k))*S + NT + j] = sv;
  }
}

// 2-pass rule prep -> fp8 e4m3.
__global__ __launch_bounds__(256) void rule_prep(const float* __restrict__ rule,
                                                 float* __restrict__ m_rule,
                                                 unsigned char* __restrict__ erule8){
  int p = blockIdx.x, b = blockIdx.y, tid = threadIdx.x;
  size_t base = (size_t)(b*NT + p) * SS;
  size_t obase = (size_t)(b*NT + p) * KK;
  const float4* r4 = (const float4*)(rule + base);
  float lm = NEGF;
  for (int i = tid; i < SS/4; i += 256){
    float4 v = r4[i];
    lm = fmaxf(fmaxf(lm, fmaxf(v.x, v.y)), fmaxf(v.z, v.w));
  }
  #pragma unroll
  for (int off = 32; off > 0; off >>= 1) lm = fmaxf(lm, __shfl_xor(lm, off));
  __shared__ float wmax[4];
  __shared__ float sm;
  if ((tid & 63) == 0) wmax[tid >> 6] = lm;
  __syncthreads();
  if (tid == 0){
    float m = fmaxf(fmaxf(wmax[0], wmax[1]), fmaxf(wmax[2], wmax[3]));
    m_rule[b*NT + p] = m;
    sm = m;
  }
  __syncthreads();
  float m = sm;
  for (int idx = tid; idx < S * 24; idx += 256){
    int l = idx / 24, q4 = idx - l * 24;
    int r = q4 * 4;
    float e[4];
    #pragma unroll
    for (int j = 0; j < 4; ++j){
      int rr = r + j;
      e[j] = (rr < S) ? __expf(rule[base + l*S + rr] - m) : 0.f;
    }
    *(unsigned int*)&erule8[obase + l*KP + r] = pk4_e4m3(e[0], e[1], e[2], e[3]);
  }
}

// Per span (b,s) of width w: O[l,r] = sum_k el[k,l]*er[k,r] via bf16 MFMA.
// R18: previous width's finalize FOLDED IN (R12 pattern + R17 Cpart layout):
// each block computes child cells sp=s, sp=s+1 from Cpart (contiguous reads),
// substitutes them at k=K-1 / k=0, and writes sp=s (last block also sp=ns)
// to global E/mb for FUTURE launches only. Race-free, fence-free.
__global__ __launch_bounds__(256) void stage1(int w, int ns,
                                              const float* __restrict__ Cpart,
                                              const float* __restrict__ m_rule,
                                              const float* __restrict__ MbufPrev,
                                              float* __restrict__ MbufCur,
                                              short* __restrict__ E_L,
                                              short* __restrict__ E_R,
                                              float* __restrict__ mb,
                                              unsigned char* __restrict__ Og8){
  int s = blockIdx.x, b = blockIdx.y, e = s + w, tid = threadIdx.x;
  int K = w - 1;
  int Kpad = (K + 31) & ~31;          // 32 or 64
  __shared__ float stmp[NSMAX];
  __shared__ float cK[NSMAX];
  __shared__ float sM;
  __shared__ float qs[2][32];
  __shared__ float cmax[2];
  __shared__ float cmb[2];
  __shared__ __align__(16) short sbuf[2 * S1R * S1STR];  // 27.6 KB
  short* elT = sbuf;
  short* erT = sbuf + S1R * S1STR;

  bool hasInline = (w >= 3);
  if (hasInline){
    // inline finalize of width-(w-1) cells sp=s (c=0) and sp=s+1 (c=1)
    for (int idx = tid; idx < 2*NT; idx += 256){
      int c = (idx >= NT) ? 1 : 0;
      int p = idx - c*NT;
      int sp = s + c;
      float sum = 0.f;
      #pragma unroll
      for (int kc = 0; kc < KSPL; ++kc)
        sum += Cpart[((size_t)(kc*B + b))*CELLSP + sp*32 + p];
      qs[c][p] = sum * __expf(m_rule[b*NT + p]);
    }
  }
  __syncthreads();
  if (hasInline && tid < 2){
    float m = 1e-37f;
    for (int p = 0; p < NT; ++p) m = fmaxf(m, qs[tid][p]);
    cmax[tid] = m;
    cmb[tid] = MbufPrev[b*NSMAX + (s + tid)] + __logf(m);
  }
  __syncthreads();

  if (hasInline){
    // writer duty for future launches (values deterministic across blocks)
    int wp = w - 1;
    if (tid < 15){
      float inv = 1.f / cmax[0];
      unsigned int pk = (unsigned int)(unsigned short)f2bs(qs[0][2*tid] * inv) |
                        ((unsigned int)(unsigned short)f2bs(qs[0][2*tid+1] * inv) << 16);
      *(unsigned int*)&E_L[((size_t)((b*NP1 + s)*NP1 + s + wp))*S + 2*tid] = pk;
      *(unsigned int*)&E_R[((size_t)((b*NP1 + s + wp)*NP1 + s))*S + 2*tid] = pk;
    } else if (tid >= 32 && tid < 47 && s == ns - 1){
      int t2 = tid - 32;
      float inv = 1.f / cmax[1];
      unsigned int pk = (unsigned int)(unsigned short)f2bs(qs[1][2*t2] * inv) |
                        ((unsigned int)(unsigned short)f2bs(qs[1][2*t2+1] * inv) << 16);
      *(unsigned int*)&E_L[((size_t)((b*NP1 + s + 1)*NP1 + s + 1 + wp))*S + 2*t2] = pk;
      *(unsigned int*)&E_R[((size_t)((b*NP1 + s + 1 + wp)*NP1 + s + 1))*S + 2*t2] = pk;
    }
    if (tid == 0) mb[(b*NP1 + s)*NP1 + (s + wp)] = cmb[0];
    if (tid == 16 && s == ns - 1) mb[(b*NP1 + s + 1)*NP1 + (s + 1 + wp)] = cmb[1];
  }

  if (tid < K){
    int u = s + tid + 1;
    float ml = (hasInline && tid == K - 1) ? cmb[0] : mb[(b*NP1 + s)*NP1 + u];
    float mr = (hasInline && tid == 0)     ? cmb[1] : mb[(b*NP1 + u)*NP1 + e];
    stmp[tid] = ml + mr;
  }
  __syncthreads();
  if (tid == 0){
    float M = NEGF;
    for (int k = 0; k < K; ++k) M = fmaxf(M, stmp[k]);
    sM = M;
    MbufCur[b*NSMAX + s] = M;
  }
  __syncthreads();
  float M = sM;
  if (tid < K) cK[tid] = __expf(stmp[tid] - M);
  __syncthreads();

  // contiguous bases: left children rows (s,u) u=s+1..s+K; right rows (u,e)
  const short* baseL = E_L + ((size_t)((b*NP1 + s)*NP1 + s + 1)) * S;
  const short* baseR = E_R + ((size_t)((b*NP1 + e)*NP1 + s + 1)) * S;

  int items = Kpad * 48;               // 48 uint pairs per k (45 data + 3 pad)
  for (int idx = tid; idx < items; idx += 256){
    int k = idx / 48, j = idx - k * 48;
    int i = 2 * j;
    short v0 = 0, v1 = 0, r0 = 0, r1 = 0;
    if (k < K && j < 45){
      // pair j<15 -> i<30 (nonterminals); j>=15 -> i>=30 (terminals)
      bool lOK = (k == 0)     ? (j >= 15) : (j < 15);
      bool rOK = (k == K - 1) ? (j >= 15) : (j < 15);
      float ck = cK[k];
      if (lOK){
        float f0, f1;
        if (hasInline && k == K - 1){
          float inv = 1.f / cmax[0];
          f0 = qs[0][i] * inv * ck;
          f1 = qs[0][i+1] * inv * ck;
        } else {
          unsigned int L = *(const unsigned int*)(baseL + k*S + i);
          f0 = __uint_as_float(L << 16) * ck;
          f1 = __uint_as_float(L & 0xFFFF0000u) * ck;
        }
        v0 = f2bs(f0);
        v1 = f2bs(f1);
      }
      if (rOK){
        if (hasInline && k == 0){
          float inv = 1.f / cmax[1];
          r0 = f2bs(qs[1][i] * inv);
          r1 = f2bs(qs[1][i+1] * inv);
        } else {
          unsigned int R = *(const unsigned int*)(baseR + k*S + i);
          r0 = (short)(R & 0xFFFFu);
          r1 = (short)(R >> 16);
        }
      }
    }
    elT[i*S1STR + k]     = v0;
    elT[(i+1)*S1STR + k] = v1;
    erT[i*S1STR + k]     = r0;
    erT[(i+1)*S1STR + k] = r1;
  }
  __syncthreads();

  int wid = tid >> 6, lane = tid & 63;
  int rr = lane & 15, hi = lane >> 4;
  int ksteps = Kpad >> 5;
  f32x4 accs[9];
  #pragma unroll
  for (int j = 0; j < 9; ++j){           // 36 tiles over 4 waves
    int t = wid * 9 + j;
    int tr = t / 6, tc = t - tr * 6;
    int ar = tr*16 + rr, br = tc*16 + rr;
    f32x4 acc = {0.f, 0.f, 0.f, 0.f};
    for (int ks = 0; ks < ksteps; ++ks){
      int kb = ks*32 + hi*8;
      bf16x8 af = *(bf16x8*)&elT[ar*S1STR + kb];
      bf16x8 bf2 = *(bf16x8*)&erT[br*S1STR + kb];
      acc = __builtin_amdgcn_mfma_f32_16x16x32_bf16(af, bf2, acc, 0, 0, 0);
    }
    accs[j] = acc;
  }
  __syncthreads();                        // all elT/erT reads done; sbuf reusable

  // repack: fp8 O tile, linear [l*96 + r] bytes in sbuf, then uint4 stores
  unsigned char* rep = (unsigned char*)sbuf;
  for (int idx = tid; idx < S * (KP - S); idx += 256){
    int l = idx / (KP - S), c = idx - l * (KP - S);
    rep[l*KP + S + c] = 0;
  }
  #pragma unroll
  for (int j = 0; j < 9; ++j){
    int t = wid * 9 + j;
    int tr = t / 6, tc = t - tr * 6;
    int rcol = tc*16 + rr;
    if (rcol < S){
      unsigned int pk = pk4_e4m3(accs[j][0], accs[j][1], accs[j][2], accs[j][3]);
      #pragma unroll
      for (int q = 0; q < 4; ++q){
        int l = tr*16 + hi*4 + q;
        if (l < S) rep[l*KP + rcol] = (unsigned char)((pk >> (8*q)) & 0xff);
      }
    }
  }
  __syncthreads();

  size_t obase = ((size_t)(b*NSMAX + s)) * KK;
  uint4* dst = (uint4*)(Og8 + obase);
  const uint4* src = (const uint4*)rep;
  for (int i = tid; i < KK/16; i += 256) dst[i] = src[i];
}

// fp8 MFMA split-K GEMM; Cpart cell layout [s*32 + p] -> one float4 store/lane.
__global__ __launch_bounds__(512) void stage2(int ns, int ntiles,
                                              const unsigned char* __restrict__ erule8,
                                              const unsigned char* __restrict__ Og8,
                                              float* __restrict__ Cpart){
  int kc = blockIdx.x, b = blockIdx.y, tid = threadIdx.x;
  __shared__ __align__(16) unsigned char ldsb[2 * MTOTB];   // 13.8 KB (dbuf)
  int wid = tid >> 6, lane = tid & 63;
  int mt = wid & 1, nt = wid >> 1;
  f32x4 acc = {0.f, 0.f, 0.f, 0.f};

  for (int i = tid; i < 2*MTOTB/4; i += 512) ((unsigned int*)ldsb)[i] = 0;

  int slot = tid & 7;
  int aRow = (tid >> 3) & 31;
  bool aDo = (tid < 256) && (aRow < NT);
  int bRow = tid >> 3;
  bool bDo = bRow < ns;
  const unsigned char* aSrc = erule8 + ((size_t)(b*NT + (aDo ? aRow : 0))) * KK + slot * 8;
  const unsigned char* bSrc = Og8    + ((size_t)(b*NSMAX + (bDo ? bRow : 0))) * KK + slot * 8;
  int aOff = aRow * ROWB + slot * 8;
  int bOff = AOFFB + bRow * ROWB + slot * 8;

  int arow = mt*16 + (lane & 15);
  int brow = nt*16 + (lane & 15);
  int hi = lane >> 4;
  bool active = nt < ntiles;
  int t0 = kc * TPC;

  uint2 ra, rb;
  if (aDo) ra = *(const uint2*)(aSrc + (size_t)t0 * KT2B);
  if (bDo) rb = *(const uint2*)(bSrc + (size_t)t0 * KT2B);
  __syncthreads();

  int cur = 0;
  for (int tt = 0; tt < TPC; ++tt){
    if (aDo) *(uint2*)&ldsb[cur*MTOTB + aOff] = ra;
    if (bDo) *(uint2*)&ldsb[cur*MTOTB + bOff] = rb;
    if (tt + 1 < TPC){
      size_t koff = (size_t)(t0 + tt + 1) * KT2B;
      if (aDo) ra = *(const uint2*)(aSrc + koff);
      if (bDo) rb = *(const uint2*)(bSrc + koff);
    }
    __syncthreads();
    if (active){
      #pragma unroll
      for (int ks = 0; ks < 2; ++ks){
        int sb = ks*4 + hi;
        long af = *(const long*)&ldsb[cur*MTOTB + arow*ROWB + sb*8];
        long bf2 = *(const long*)&ldsb[cur*MTOTB + AOFFB + brow*ROWB + sb*8];
        acc = __builtin_amdgcn_mfma_f32_16x16x32_fp8_fp8(af, bf2, acc, 0, 0, 0);
      }
    }
    cur ^= 1;
  }

  if (active){
    int scol = nt*16 + (lane & 15);
    if (scol < ns){
      int p0 = mt*16 + hi*4;           // acc[r] -> p = p0 + r (contiguous)
      float* cp = Cpart + ((size_t)(kc*B + b)) * CELLSP + scol*32 + p0;
      *(f32x4*)cp = acc;               // p=30,31 overflow lands in padding
    }
  }
}

// Root: beta(w=50) computed directly from Cpart (ns=1: cell = p).
__global__ void root_lse(const float* __restrict__ Cpart, const float* __restrict__ Mbuf,
                         const float* __restrict__ m_rule, const float* __restrict__ root,
                         float* __restrict__ out){
  int b = blockIdx.x, j = threadIdx.x;
  float v = NEGF;
  if (j < NT){
    float sum = 0.f;
    #pragma unroll
    for (int q = 0; q < KSPL; ++q)
      sum += Cpart[((size_t)(q*B + b))*CELLSP + j];
    v = __logf(fmaxf(sum, 1e-37f)) + Mbuf[b*NSMAX + 0]
      + m_rule[b*NT + j] + root[b*NT + j];
  }
  float m = v;
  #pragma unroll
  for (int off = 32; off > 0; off >>= 1) m = fmaxf(m, __shfl_xor(m, off));
  float ex = __expf(v - m);
  #pragma unroll
  for (int off = 32; off > 0; off >>= 1) ex += __shfl_xor(ex, off);
  if (j == 0) out[b] = __logf(ex) + m;
}

} // namespace

extern "C" void kernel_launch(void* const* d_in, const int* in_sizes, int n_in,
                              void* d_out, int out_size, void* d_ws, size_t ws_size,
                              hipStream_t stream){
  (void)in_sizes; (void)n_in; (void)out_size; (void)ws_size;
  const float* unary = (const float*)d_in[0];
  const float* rule  = (const float*)d_in[1];
  const float* root  = (const float*)d_in[2];

  char* ws = (char*)d_ws;
  size_t off = 0;
  auto alloc = [&](size_t bytes) -> void* {
    void* p = ws + off;
    off += (bytes + 255) & ~(size_t)255;
    return p;
  };
  float* mb     = (float*)alloc(sizeof(float) * (size_t)B * NP1 * NP1);
  float* m_rule = (float*)alloc(sizeof(float) * B * NT);
  float* Mbuf   = (float*)alloc(sizeof(float) * 2 * B * NSMAX);   // parity dbuf
  float* Cpart  = (float*)alloc(sizeof(float) * KSPL * B * CELLSP);  // 6.1 MB
  short* E_L    = (short*)alloc(sizeof(short) * (size_t)ECOUNT);     // 30 MB
  short* E_R    = (short*)alloc(sizeof(short) * (size_t)ECOUNT);     // 30 MB
  unsigned char* erule8 = (unsigned char*)alloc((size_t)B * NT * KK);    // 16.6 MB
  unsigned char* Og8    = (unsigned char*)alloc((size_t)B * NSMAX * KK); // 27.1 MB

  unary_init<<<dim3(N, B), dim3(64), 0, stream>>>(unary, mb, E_L, E_R);
  rule_prep<<<dim3(NT, B), dim3(256), 0, stream>>>(rule, m_rule, erule8);

  for (int w = 2; w <= N; ++w){
    int ns = N - w + 1;
    int ntiles = (ns + 15) >> 4;
    const float* mprev = Mbuf + ((size_t)((w - 1) & 1)) * B * NSMAX;
    float*       mcur  = Mbuf + ((size_t)(w & 1)) * B * NSMAX;
    stage1<<<dim3(ns, B), dim3(256), 0, stream>>>(w, ns, Cpart, m_rule,
                                                  mprev, mcur, E_L, E_R, mb, Og8);
    stage2<<<dim3(KSPL, B), dim3(512), 0, stream>>>(ns, ntiles, erule8, Og8, Cpart);
  }
  // w=50 parity: 50&1 == 0 -> Mbuf first half holds M for width 50
  root_lse<<<dim3(B), dim3(64), 0, stream>>>(Cpart, Mbuf, m_rule, root, (float*)d_out);
}

// Round 19
// 1468.732 us; speedup vs baseline: 2.3710x; 1.0391x over previous
//
#include <hip/hip_runtime.h>
#include <hip/hip_bf16.h>

#define NEGF (-1000000000.0f)

namespace {

constexpr int B  = 64;
constexpr int N  = 50;
constexpr int NT = 30;
constexpr int T  = 60;
constexpr int S  = 90;          // NT + T
constexpr int NP1 = N + 1;      // 51
constexpr int NSMAX = N - 1;    // 49
constexpr int SS = S * S;       // 8100
constexpr int CELLSP = NSMAX * 32 + 32;  // padded cells (stride 32 per span)
constexpr int ECOUNT = B * NP1 * NP1 * S;

// ---- padded K layout (BYTES: fp8 = 1 B/element) ----
constexpr int KP  = 96;          // padded r-dim per l (pads are exact 0)
constexpr int KK  = S * KP;      // 8640 elements = bytes
constexpr int KSPL = 15;         // split-K chunks
constexpr int KT2B = 64;         // K-tile bytes per row slice
constexpr int NKT = KK / KT2B;   // 135
constexpr int TPC = NKT / KSPL;  // 9 tiles per chunk
constexpr int ROWB  = 72;        // stage2 LDS row stride bytes
constexpr int AOFFB = 32 * ROWB;
constexpr int MTOTB = (32 + 64) * ROWB;       // 6912 B per buffer

// ---- stage1 MFMA layout (bf16 internal) ----
constexpr int S1R = 96;          // padded state rows: 6 tiles of 16
constexpr int S1STR = 72;        // row stride in shorts (144B, b128-aligned)

using bf16x8 = __attribute__((ext_vector_type(8))) short;
using f32x4  = __attribute__((ext_vector_type(4))) float;

__device__ __forceinline__ unsigned int pk4_e4m3(float a, float b, float c, float d){
  int w = __builtin_amdgcn_cvt_pk_fp8_f32(a, b, 0, false);
  w = __builtin_amdgcn_cvt_pk_fp8_f32(c, d, w, true);
  return (unsigned int)w;
}
__device__ __forceinline__ short f2bs(float v){
  __hip_bfloat16 h = __float2bfloat16(v);
  return *reinterpret_cast<short*>(&h);
}

// width-1 spans: mb = state max; E_L/E_R = bf16(exp(unary - mb)) terminal slots.
__global__ void unary_init(const float* __restrict__ unary, float* __restrict__ mb,
                           short* __restrict__ E_L, short* __restrict__ E_R){
  int k = blockIdx.x, b = blockIdx.y, j = threadIdx.x;
  float v = (j < T) ? unary[(b*N + k)*T + j] : NEGF;
  float m = v;
  #pragma unroll
  for (int off = 32; off > 0; off >>= 1) m = fmaxf(m, __shfl_xor(m, off));
  if (j == 0) mb[(b*NP1 + k)*NP1 + (k+1)] = m;
  if (j < T){
    short sv = f2bs(__expf(v - m));
    E_L[((size_t)((b*NP1 + k)*NP1 + (k+1)))*S + NT + j] = sv;
    E_R[((size_t)((b*NP1 + (k+1))*NP1 + k))*S + NT + j] = sv;
  }
}

// 2-pass rule prep -> fp8 e4m3.
__global__ __launch_bounds__(256) void rule_prep(const float* __restrict__ rule,
                                                 float* __restrict__ m_rule,
                                                 unsigned char* __restrict__ erule8){
  int p = blockIdx.x, b = blockIdx.y, tid = threadIdx.x;
  size_t base = (size_t)(b*NT + p) * SS;
  size_t obase = (size_t)(b*NT + p) * KK;
  const float4* r4 = (const float4*)(rule + base);
  float lm = NEGF;
  for (int i = tid; i < SS/4; i += 256){
    float4 v = r4[i];
    lm = fmaxf(fmaxf(lm, fmaxf(v.x, v.y)), fmaxf(v.z, v.w));
  }
  #pragma unroll
  for (int off = 32; off > 0; off >>= 1) lm = fmaxf(lm, __shfl_xor(lm, off));
  __shared__ float wmax[4];
  __shared__ float sm;
  if ((tid & 63) == 0) wmax[tid >> 6] = lm;
  __syncthreads();
  if (tid == 0){
    float m = fmaxf(fmaxf(wmax[0], wmax[1]), fmaxf(wmax[2], wmax[3]));
    m_rule[b*NT + p] = m;
    sm = m;
  }
  __syncthreads();
  float m = sm;
  for (int idx = tid; idx < S * 24; idx += 256){
    int l = idx / 24, q4 = idx - l * 24;
    int r = q4 * 4;
    float e[4];
    #pragma unroll
    for (int j = 0; j < 4; ++j){
      int rr = r + j;
      e[j] = (rr < S) ? __expf(rule[base + l*S + rr] - m) : 0.f;
    }
    *(unsigned int*)&erule8[obase + l*KP + r] = pk4_e4m3(e[0], e[1], e[2], e[3]);
  }
}

// Per span (b,s) of width w: O[l,r] = sum_k el[k,l]*er[k,r] via bf16 MFMA.
// R19: XOR k-block swizzle (blk ^= (row>>1)&kmask) on elT/erT write AND read
// -> staging LDS writes conflict-free (was ~8-way, 3.05M conflicts measured).
__global__ __launch_bounds__(256) void stage1(int w, int ns,
                                              const float* __restrict__ Cpart,
                                              const float* __restrict__ m_rule,
                                              const float* __restrict__ MbufPrev,
                                              float* __restrict__ MbufCur,
                                              short* __restrict__ E_L,
                                              short* __restrict__ E_R,
                                              float* __restrict__ mb,
                                              unsigned char* __restrict__ Og8){
  int s = blockIdx.x, b = blockIdx.y, e = s + w, tid = threadIdx.x;
  int K = w - 1;
  int Kpad = (K + 31) & ~31;          // 32 or 64
  int kmask = (Kpad >> 3) - 1;        // 3 or 7
  __shared__ float stmp[NSMAX];
  __shared__ float cK[NSMAX];
  __shared__ float sM;
  __shared__ float qs[2][32];
  __shared__ float cmax[2];
  __shared__ float cmb[2];
  __shared__ __align__(16) short sbuf[2 * S1R * S1STR];  // 27.6 KB
  short* elT = sbuf;
  short* erT = sbuf + S1R * S1STR;

  bool hasInline = (w >= 3);
  if (hasInline){
    // inline finalize of width-(w-1) cells sp=s (c=0) and sp=s+1 (c=1)
    for (int idx = tid; idx < 2*NT; idx += 256){
      int c = (idx >= NT) ? 1 : 0;
      int p = idx - c*NT;
      int sp = s + c;
      float sum = 0.f;
      #pragma unroll
      for (int kc = 0; kc < KSPL; ++kc)
        sum += Cpart[((size_t)(kc*B + b))*CELLSP + sp*32 + p];
      qs[c][p] = sum * __expf(m_rule[b*NT + p]);
    }
  }
  __syncthreads();
  if (hasInline && tid < 2){
    float m = 1e-37f;
    for (int p = 0; p < NT; ++p) m = fmaxf(m, qs[tid][p]);
    cmax[tid] = m;
    cmb[tid] = MbufPrev[b*NSMAX + (s + tid)] + __logf(m);
  }
  __syncthreads();

  if (hasInline){
    // writer duty for future launches (values deterministic across blocks)
    int wp = w - 1;
    if (tid < 15){
      float inv = 1.f / cmax[0];
      unsigned int pk = (unsigned int)(unsigned short)f2bs(qs[0][2*tid] * inv) |
                        ((unsigned int)(unsigned short)f2bs(qs[0][2*tid+1] * inv) << 16);
      *(unsigned int*)&E_L[((size_t)((b*NP1 + s)*NP1 + s + wp))*S + 2*tid] = pk;
      *(unsigned int*)&E_R[((size_t)((b*NP1 + s + wp)*NP1 + s))*S + 2*tid] = pk;
    } else if (tid >= 32 && tid < 47 && s == ns - 1){
      int t2 = tid - 32;
      float inv = 1.f / cmax[1];
      unsigned int pk = (unsigned int)(unsigned short)f2bs(qs[1][2*t2] * inv) |
                        ((unsigned int)(unsigned short)f2bs(qs[1][2*t2+1] * inv) << 16);
      *(unsigned int*)&E_L[((size_t)((b*NP1 + s + 1)*NP1 + s + 1 + wp))*S + 2*t2] = pk;
      *(unsigned int*)&E_R[((size_t)((b*NP1 + s + 1 + wp)*NP1 + s + 1))*S + 2*t2] = pk;
    }
    if (tid == 0) mb[(b*NP1 + s)*NP1 + (s + wp)] = cmb[0];
    if (tid == 16 && s == ns - 1) mb[(b*NP1 + s + 1)*NP1 + (s + 1 + wp)] = cmb[1];
  }

  if (tid < K){
    int u = s + tid + 1;
    float ml = (hasInline && tid == K - 1) ? cmb[0] : mb[(b*NP1 + s)*NP1 + u];
    float mr = (hasInline && tid == 0)     ? cmb[1] : mb[(b*NP1 + u)*NP1 + e];
    stmp[tid] = ml + mr;
  }
  __syncthreads();
  if (tid == 0){
    float M = NEGF;
    for (int k = 0; k < K; ++k) M = fmaxf(M, stmp[k]);
    sM = M;
    MbufCur[b*NSMAX + s] = M;
  }
  __syncthreads();
  float M = sM;
  if (tid < K) cK[tid] = __expf(stmp[tid] - M);
  __syncthreads();

  // contiguous bases: left children rows (s,u) u=s+1..s+K; right rows (u,e)
  const short* baseL = E_L + ((size_t)((b*NP1 + s)*NP1 + s + 1)) * S;
  const short* baseR = E_R + ((size_t)((b*NP1 + e)*NP1 + s + 1)) * S;

  int items = Kpad * 48;               // 48 uint pairs per k (45 data + 3 pad)
  for (int idx = tid; idx < items; idx += 256){
    int k = idx / 48, j = idx - k * 48;
    int i = 2 * j;
    short v0 = 0, v1 = 0, r0 = 0, r1 = 0;
    if (k < K && j < 45){
      // pair j<15 -> i<30 (nonterminals); j>=15 -> i>=30 (terminals)
      bool lOK = (k == 0)     ? (j >= 15) : (j < 15);
      bool rOK = (k == K - 1) ? (j >= 15) : (j < 15);
      float ck = cK[k];
      if (lOK){
        float f0, f1;
        if (hasInline && k == K - 1){
          float inv = 1.f / cmax[0];
          f0 = qs[0][i] * inv * ck;
          f1 = qs[0][i+1] * inv * ck;
        } else {
          unsigned int L = *(const unsigned int*)(baseL + k*S + i);
          f0 = __uint_as_float(L << 16) * ck;
          f1 = __uint_as_float(L & 0xFFFF0000u) * ck;
        }
        v0 = f2bs(f0);
        v1 = f2bs(f1);
      }
      if (rOK){
        if (hasInline && k == 0){
          float inv = 1.f / cmax[1];
          r0 = f2bs(qs[1][i] * inv);
          r1 = f2bs(qs[1][i+1] * inv);
        } else {
          unsigned int R = *(const unsigned int*)(baseR + k*S + i);
          r0 = (short)(R & 0xFFFFu);
          r1 = (short)(R >> 16);
        }
      }
    }
    // swizzled column: block (k>>3) ^ ((i>>1)&kmask); rows i,i+1 share i>>1
    int kk7 = k & 7;
    int swc = (((k >> 3) ^ ((i >> 1) & kmask)) << 3) + kk7;
    elT[i*S1STR + swc]     = v0;
    elT[(i+1)*S1STR + swc] = v1;
    erT[i*S1STR + swc]     = r0;
    erT[(i+1)*S1STR + swc] = r1;
  }
  __syncthreads();

  int wid = tid >> 6, lane = tid & 63;
  int rr = lane & 15, hi = lane >> 4;
  int ksteps = Kpad >> 5;
  f32x4 accs[9];
  #pragma unroll
  for (int j = 0; j < 9; ++j){           // 36 tiles over 4 waves
    int t = wid * 9 + j;
    int tr = t / 6, tc = t - tr * 6;
    int ar = tr*16 + rr, br = tc*16 + rr;
    f32x4 acc = {0.f, 0.f, 0.f, 0.f};
    for (int ks = 0; ks < ksteps; ++ks){
      int kb = ks*4 + hi;
      bf16x8 af = *(bf16x8*)&elT[ar*S1STR + ((kb ^ ((ar >> 1) & kmask)) << 3)];
      bf16x8 bf2 = *(bf16x8*)&erT[br*S1STR + ((kb ^ ((br >> 1) & kmask)) << 3)];
      acc = __builtin_amdgcn_mfma_f32_16x16x32_bf16(af, bf2, acc, 0, 0, 0);
    }
    accs[j] = acc;
  }
  __syncthreads();                        // all elT/erT reads done; sbuf reusable

  // repack: fp8 O tile, linear [l*96 + r] bytes in sbuf, then uint4 stores
  unsigned char* rep = (unsigned char*)sbuf;
  for (int idx = tid; idx < S * (KP - S); idx += 256){
    int l = idx / (KP - S), c = idx - l * (KP - S);
    rep[l*KP + S + c] = 0;
  }
  #pragma unroll
  for (int j = 0; j < 9; ++j){
    int t = wid * 9 + j;
    int tr = t / 6, tc = t - tr * 6;
    int rcol = tc*16 + rr;
    if (rcol < S){
      unsigned int pk = pk4_e4m3(accs[j][0], accs[j][1], accs[j][2], accs[j][3]);
      #pragma unroll
      for (int q = 0; q < 4; ++q){
        int l = tr*16 + hi*4 + q;
        if (l < S) rep[l*KP + rcol] = (unsigned char)((pk >> (8*q)) & 0xff);
      }
    }
  }
  __syncthreads();

  size_t obase = ((size_t)(b*NSMAX + s)) * KK;
  uint4* dst = (uint4*)(Og8 + obase);
  const uint4* src = (const uint4*)rep;
  for (int i = tid; i < KK/16; i += 256) dst[i] = src[i];
}

// fp8 MFMA split-K GEMM; R19: no LDS zero-fill — out-of-range rows stage
// clamped (replicated) real data whose products land only in discarded slots.
__global__ __launch_bounds__(512) void stage2(int ns, int ntiles,
                                              const unsigned char* __restrict__ erule8,
                                              const unsigned char* __restrict__ Og8,
                                              float* __restrict__ Cpart){
  int kc = blockIdx.x, b = blockIdx.y, tid = threadIdx.x;
  __shared__ __align__(16) unsigned char ldsb[2 * MTOTB];   // 13.8 KB (dbuf)
  int wid = tid >> 6, lane = tid & 63;
  int mt = wid & 1, nt = wid >> 1;
  f32x4 acc = {0.f, 0.f, 0.f, 0.f};

  int slot = tid & 7;
  int aRow = (tid >> 3) & 31;
  int aRowS = aRow < NT ? aRow : NT - 1;      // clamp: rows 30,31 replicate 29
  bool aDo = (tid < 256);
  int bRow = tid >> 3;
  int bRowS = bRow < ns ? bRow : ns - 1;      // clamp
  const unsigned char* aSrc = erule8 + ((size_t)(b*NT + aRowS)) * KK + slot * 8;
  const unsigned char* bSrc = Og8    + ((size_t)(b*NSMAX + bRowS)) * KK + slot * 8;
  int aOff = aRow * ROWB + slot * 8;
  int bOff = AOFFB + bRow * ROWB + slot * 8;

  int arow = mt*16 + (lane & 15);
  int brow = nt*16 + (lane & 15);
  int hi = lane >> 4;
  bool active = nt < ntiles;
  int t0 = kc * TPC;

  uint2 ra, rb;
  if (aDo) ra = *(const uint2*)(aSrc + (size_t)t0 * KT2B);
  rb = *(const uint2*)(bSrc + (size_t)t0 * KT2B);

  int cur = 0;
  for (int tt = 0; tt < TPC; ++tt){
    if (aDo) *(uint2*)&ldsb[cur*MTOTB + aOff] = ra;
    *(uint2*)&ldsb[cur*MTOTB + bOff] = rb;
    if (tt + 1 < TPC){
      size_t koff = (size_t)(t0 + tt + 1) * KT2B;
      if (aDo) ra = *(const uint2*)(aSrc + koff);
      rb = *(const uint2*)(bSrc + koff);
    }
    __syncthreads();   // buf[cur] staged; compute(tt-1) on buf[cur^1] done
    if (active){
      #pragma unroll
      for (int ks = 0; ks < 2; ++ks){
        int sb = ks*4 + hi;
        long af = *(const long*)&ldsb[cur*MTOTB + arow*ROWB + sb*8];
        long bf2 = *(const long*)&ldsb[cur*MTOTB + AOFFB + brow*ROWB + sb*8];
        acc = __builtin_amdgcn_mfma_f32_16x16x32_fp8_fp8(af, bf2, acc, 0, 0, 0);
      }
    }
    cur ^= 1;
  }

  if (active){
    int scol = nt*16 + (lane & 15);
    if (scol < ns){
      int p0 = mt*16 + hi*4;           // acc[r] -> p = p0 + r (contiguous)
      float* cp = Cpart + ((size_t)(kc*B + b)) * CELLSP + scol*32 + p0;
      *(f32x4*)cp = acc;               // p=30,31 overflow lands in padding
    }
  }
}

// Root: beta(w=50) computed directly from Cpart (ns=1: cell = p).
__global__ void root_lse(const float* __restrict__ Cpart, const float* __restrict__ Mbuf,
                         const float* __restrict__ m_rule, const float* __restrict__ root,
                         float* __restrict__ out){
  int b = blockIdx.x, j = threadIdx.x;
  float v = NEGF;
  if (j < NT){
    float sum = 0.f;
    #pragma unroll
    for (int q = 0; q < KSPL; ++q)
      sum += Cpart[((size_t)(q*B + b))*CELLSP + j];
    v = __logf(fmaxf(sum, 1e-37f)) + Mbuf[b*NSMAX + 0]
      + m_rule[b*NT + j] + root[b*NT + j];
  }
  float m = v;
  #pragma unroll
  for (int off = 32; off > 0; off >>= 1) m = fmaxf(m, __shfl_xor(m, off));
  float ex = __expf(v - m);
  #pragma unroll
  for (int off = 32; off > 0; off >>= 1) ex += __shfl_xor(ex, off);
  if (j == 0) out[b] = __logf(ex) + m;
}

} // namespace

extern "C" void kernel_launch(void* const* d_in, const int* in_sizes, int n_in,
                              void* d_out, int out_size, void* d_ws, size_t ws_size,
                              hipStream_t stream){
  (void)in_sizes; (void)n_in; (void)out_size; (void)ws_size;
  const float* unary = (const float*)d_in[0];
  const float* rule  = (const float*)d_in[1];
  const float* root  = (const float*)d_in[2];

  char* ws = (char*)d_ws;
  size_t off = 0;
  auto alloc = [&](size_t bytes) -> void* {
    void* p = ws + off;
    off += (bytes + 255) & ~(size_t)255;
    return p;
  };
  float* mb     = (float*)alloc(sizeof(float) * (size_t)B * NP1 * NP1);
  float* m_rule = (float*)alloc(sizeof(float) * B * NT);
  float* Mbuf   = (float*)alloc(sizeof(float) * 2 * B * NSMAX);   // parity dbuf
  float* Cpart  = (float*)alloc(sizeof(float) * KSPL * B * CELLSP);  // 6.1 MB
  short* E_L    = (short*)alloc(sizeof(short) * (size_t)ECOUNT);     // 30 MB
  short* E_R    = (short*)alloc(sizeof(short) * (size_t)ECOUNT);     // 30 MB
  unsigned char* erule8 = (unsigned char*)alloc((size_t)B * NT * KK);    // 16.6 MB
  unsigned char* Og8    = (unsigned char*)alloc((size_t)B * NSMAX * KK); // 27.1 MB

  unary_init<<<dim3(N, B), dim3(64), 0, stream>>>(unary, mb, E_L, E_R);
  rule_prep<<<dim3(NT, B), dim3(256), 0, stream>>>(rule, m_rule, erule8);

  for (int w = 2; w <= N; ++w){
    int ns = N - w + 1;
    int ntiles = (ns + 15) >> 4;
    const float* mprev = Mbuf + ((size_t)((w - 1) & 1)) * B * NSMAX;
    float*       mcur  = Mbuf + ((size_t)(w & 1)) * B * NSMAX;
    stage1<<<dim3(ns, B), dim3(256), 0, stream>>>(w, ns, Cpart, m_rule,
                                                  mprev, mcur, E_L, E_R, mb, Og8);
    stage2<<<dim3(KSPL, B), dim3(512), 0, stream>>>(ns, ntiles, erule8, Og8, Cpart);
  }
  // w=50 parity: 50&1 == 0 -> Mbuf first half holds M for width 50
  root_lse<<<dim3(B), dim3(64), 0, stream>>>(Cpart, Mbuf, m_rule, root, (float*)d_out);
}